// Round 2
// baseline (3320.982 us; speedup 1.0000x reference)
//
#include <hip/hip_runtime.h>
#include <math.h>

#define N_NODES  500000
#define N_EDGES  8000000
#define N_GRAPHS 25000
#define SD  119   // 20+27+36+36 concatenated segment-sum dim
#define RD  175
#define H1  96
#define H2  63
#define NT  138
#define GPB 16    // graphs per block in dense kernels
#define SCAN_CHUNK 2048
#define NB_SCAN 245   // ceil(500000/2048)
#define BUCKET_SHIFT 8
#define BUCKET_NODES 256
#define NBUCK 1954    // ceil(500000/256)

static __device__ __forceinline__ float selu_f(float m){
    const float scale=1.0507009873554805f, alpha=1.6732632423543772f;
    return m > 0.0f ? scale*m : scale*alpha*(__expf(m)-1.0f);
}

// ---------------- init ----------------
__global__ void k_init(int* hist, int* gstart, int* gend){
    int i = blockIdx.x*256 + threadIdx.x;
    if(i <= N_NODES) hist[i] = 0;
    if(i <  N_GRAPHS){ gstart[i]=0; gend[i]=0; }
}

// ---------------- CSR build ----------------
__global__ void k_hist(const int* __restrict__ dst, int* __restrict__ hist){
    int e = blockIdx.x*256 + threadIdx.x;
    if(e < N_EDGES) atomicAdd(&hist[dst[e]], 1);
}

__device__ __forceinline__ int block_excl_scan_256(int v){
    __shared__ int sh[256];
    int t = threadIdx.x;
    sh[t] = v; __syncthreads();
    int acc = v;
    for(int off=1; off<256; off<<=1){
        int add = (t>=off) ? sh[t-off] : 0;
        __syncthreads();
        acc += add;
        sh[t] = acc;
        __syncthreads();
    }
    return acc - v;
}

__global__ void k_scan1(const int* __restrict__ hist, int* __restrict__ partials){
    int base = blockIdx.x*SCAN_CHUNK;
    int s = 0;
    for(int i=threadIdx.x; i<SCAN_CHUNK; i+=256){
        int idx = base+i;
        if(idx < N_NODES) s += hist[idx];
    }
    __shared__ int sh[256];
    sh[threadIdx.x]=s; __syncthreads();
    for(int off=128; off>0; off>>=1){
        if(threadIdx.x<off) sh[threadIdx.x]+=sh[threadIdx.x+off];
        __syncthreads();
    }
    if(threadIdx.x==0) partials[blockIdx.x]=sh[0];
}

__global__ void k_scan2(int* partials){
    int t = threadIdx.x;
    int v = (t<NB_SCAN) ? partials[t] : 0;
    int exc = block_excl_scan_256(v);
    if(t<NB_SCAN) partials[t]=exc;
}

__global__ void k_scan3(const int* __restrict__ hist, const int* __restrict__ partials,
                        int* __restrict__ row_ptr){
    int base = blockIdx.x*SCAN_CHUNK;
    int t = threadIdx.x;
    int local[8]; int s=0;
    #pragma unroll
    for(int i=0;i<8;i++){
        int idx = base + t*8 + i;
        int v = (idx<N_NODES) ? hist[idx] : 0;
        local[i]=s; s+=v;
    }
    int texc = block_excl_scan_256(s) + partials[blockIdx.x];
    #pragma unroll
    for(int i=0;i<8;i++){
        int idx = base + t*8 + i;
        if(idx<N_NODES) row_ptr[idx]=texc+local[i];
    }
    if(blockIdx.x==0 && t==0) row_ptr[N_NODES]=N_EDGES;
}

__global__ void k_binit(const int* __restrict__ row_ptr, int* __restrict__ bcur){
    int b = blockIdx.x*256 + threadIdx.x;
    if(b < NBUCK) bcur[b] = row_ptr[b*BUCKET_NODES];
}

// pass 1: bucket edges by dst>>8, write packed (local_dst<<19 | src)
__global__ void k_bucket(const int* __restrict__ src, const int* __restrict__ dst,
                         int* __restrict__ bcur, int* __restrict__ packed){
    int e = blockIdx.x*256 + threadIdx.x;
    if(e < N_EDGES){
        int d = dst[e];
        int b = d >> BUCKET_SHIFT;
        int pos = atomicAdd(&bcur[b], 1);
        packed[pos] = ((d & (BUCKET_NODES-1)) << 19) | src[e];
    }
}

// pass 2: one block per bucket; per-node cursors in LDS; CSR writes in 16KB window
__global__ __launch_bounds__(256) void k_scatter2(const int* __restrict__ row_ptr,
                          const int* __restrict__ packed, int* __restrict__ csr){
    __shared__ int lcur[BUCKET_NODES];
    int b = blockIdx.x;
    int t = threadIdx.x;
    int nb = b << BUCKET_SHIFT;
    int node = nb + t;
    lcur[t] = (node < N_NODES) ? row_ptr[node] : 0;
    __syncthreads();
    int ebeg = row_ptr[nb];
    int hi = nb + BUCKET_NODES; if(hi > N_NODES) hi = N_NODES;
    int eend = row_ptr[hi];
    for(int e = ebeg + t; e < eend; e += 256){
        int code = packed[e];
        int local = code >> 19;
        int s = code & 0x7FFFF;
        int pos = atomicAdd(&lcur[local], 1);
        csr[pos] = s;
    }
}

// ---------------- graph boundaries (batch is sorted) ----------------
__global__ void k_bounds(const int* __restrict__ batch, int* __restrict__ gstart, int* __restrict__ gend){
    int n = blockIdx.x*256 + threadIdx.x;
    if(n >= N_NODES) return;
    int b = batch[n];
    if(n==0        || batch[n-1]!=b) gstart[b]=n;
    if(n==N_NODES-1|| batch[n+1]!=b) gend[b]=n+1;
}

// ---------------- node transform: y[n][o] = x[n][:DIN] @ W + b, padded-out stride POUT ----------------
template<int DIN,int DOUT,int PIN,int POUT>
__global__ __launch_bounds__(256) void k_transform(const float* __restrict__ x, const float* __restrict__ W,
                                                   const float* __restrict__ bias, float* __restrict__ y){
    __shared__ float sw[DIN*DOUT];
    __shared__ float sb[DOUT];
    int t = threadIdx.x;
    for(int i=t;i<DIN*DOUT;i+=256) sw[i]=W[i];
    if(t<DOUT) sb[t]=bias[t];
    __syncthreads();
    int gid = blockIdx.x*256 + t;
    if(gid >= N_NODES*POUT) return;
    int n = gid/POUT, o = gid - n*POUT;
    if(o >= DOUT){ y[gid]=0.f; return; }   // zero pad lanes
    const float* xr = x + (size_t)n*PIN;
    float acc = sb[o];
    #pragma unroll
    for(int i=0;i<DIN;i++) acc = fmaf(xr[i], sw[i*DOUT+o], acc);
    y[gid]=acc;
}

// ---------------- aggregate (float4 gathers): xo[n][f] = selu(finite(max over in-edges)) ----------------
template<int P>   // P = padded dim, multiple of 4; FG = P/4 float4-groups per node
__global__ __launch_bounds__(256) void k_agg(const float4* __restrict__ y, const int* __restrict__ row_ptr,
                                             const int* __restrict__ csr, float4* __restrict__ xo){
    const int FG = P/4;
    int gid = blockIdx.x*256 + threadIdx.x;
    if(gid >= N_NODES*FG) return;
    int n = gid/FG, fg = gid - n*FG;
    int beg = row_ptr[n], end = row_ptr[n+1];
    float4 m = make_float4(-INFINITY,-INFINITY,-INFINITY,-INFINITY);
    int j = beg;
    for(; j+4<=end; j+=4){
        int s0=csr[j], s1=csr[j+1], s2=csr[j+2], s3=csr[j+3];
        float4 v0=y[(size_t)s0*FG+fg], v1=y[(size_t)s1*FG+fg];
        float4 v2=y[(size_t)s2*FG+fg], v3=y[(size_t)s3*FG+fg];
        m.x = fmaxf(m.x, fmaxf(fmaxf(v0.x,v1.x), fmaxf(v2.x,v3.x)));
        m.y = fmaxf(m.y, fmaxf(fmaxf(v0.y,v1.y), fmaxf(v2.y,v3.y)));
        m.z = fmaxf(m.z, fmaxf(fmaxf(v0.z,v1.z), fmaxf(v2.z,v3.z)));
        m.w = fmaxf(m.w, fmaxf(fmaxf(v0.w,v1.w), fmaxf(v2.w,v3.w)));
    }
    for(; j<end; j++){
        float4 v = y[(size_t)csr[j]*FG+fg];
        m.x=fmaxf(m.x,v.x); m.y=fmaxf(m.y,v.y); m.z=fmaxf(m.z,v.z); m.w=fmaxf(m.w,v.w);
    }
    if(!isfinite(m.x)) m.x=0.f;
    if(!isfinite(m.y)) m.y=0.f;
    if(!isfinite(m.z)) m.z=0.f;
    if(!isfinite(m.w)) m.w=0.f;
    float4 o;
    o.x=selu_f(m.x); o.y=selu_f(m.y); o.z=selu_f(m.z); o.w=selu_f(m.w);
    xo[gid]=o;
}

// ---------------- per-graph segment sum into S[:, off:off+D], input stride P ----------------
template<int D,int P>
__global__ void k_segsum(const float* __restrict__ x, const int* __restrict__ gs, const int* __restrict__ ge,
                         float* __restrict__ S, int off){
    int g = blockIdx.x; int f = threadIdx.x;
    if(f >= D) return;
    int b = gs[g], e = ge[g];
    float acc = 0.f;
    for(int n=b;n<e;n++) acc += x[(size_t)n*P+f];
    S[(size_t)g*SD + off + f] = acc;
}

// ---------------- readout: r = S @ Wcat + sum(b) ----------------
__global__ __launch_bounds__(192) void k_readout(const float* __restrict__ S,
    const float* __restrict__ w1,const float* __restrict__ b1,
    const float* __restrict__ w2,const float* __restrict__ b2,
    const float* __restrict__ w3,const float* __restrict__ b3,
    const float* __restrict__ w4,const float* __restrict__ b4,
    float* __restrict__ r){
    __shared__ float sH[GPB][SD];
    int t = threadIdx.x;
    int g0 = blockIdx.x*GPB;
    for(int i=t;i<GPB*SD;i+=192){
        int gl=i/SD, k=i-gl*SD;
        int g=g0+gl;
        sH[gl][k] = (g<N_GRAPHS) ? S[(size_t)g*SD+k] : 0.f;
    }
    __syncthreads();
    int j = t;
    if(j < RD){
        float acc[GPB];
        float bj = b1[j]+b2[j]+b3[j]+b4[j];
        #pragma unroll
        for(int gl=0;gl<GPB;gl++) acc[gl]=bj;
        for(int k=0;k<20;k++){ float wv=w1[k*RD+j];
            #pragma unroll
            for(int gl=0;gl<GPB;gl++) acc[gl] += sH[gl][k]*wv; }
        for(int k=0;k<27;k++){ float wv=w2[k*RD+j];
            #pragma unroll
            for(int gl=0;gl<GPB;gl++) acc[gl] += sH[gl][20+k]*wv; }
        for(int k=0;k<36;k++){ float wv=w3[k*RD+j];
            #pragma unroll
            for(int gl=0;gl<GPB;gl++) acc[gl] += sH[gl][47+k]*wv; }
        for(int k=0;k<36;k++){ float wv=w4[k*RD+j];
            #pragma unroll
            for(int gl=0;gl<GPB;gl++) acc[gl] += sH[gl][83+k]*wv; }
        int ng = min(GPB, N_GRAPHS-g0);
        for(int gl=0;gl<ng;gl++) r[(size_t)(g0+gl)*RD+j] = acc[gl];
    }
}

// ---------------- fc1: z1 = [r, mol] @ w + b, + BN partial stats ----------------
__global__ __launch_bounds__(128) void k_fc1(const float* __restrict__ r, const float* __restrict__ mol,
    const float* __restrict__ w, const float* __restrict__ b,
    float* __restrict__ z1, float* __restrict__ ps, float* __restrict__ pq){
    __shared__ float sH[GPB][RD+10];
    int t = threadIdx.x;
    int g0 = blockIdx.x*GPB;
    for(int i=t;i<GPB*(RD+10);i+=128){
        int gl=i/(RD+10), k=i-gl*(RD+10);
        int g=g0+gl;
        float v=0.f;
        if(g<N_GRAPHS) v = (k<RD) ? r[(size_t)g*RD+k] : mol[(size_t)g*10 + (k-RD)];
        sH[gl][k]=v;
    }
    __syncthreads();
    int j = t;
    if(j < H1){
        float acc[GPB]; float bj=b[j];
        #pragma unroll
        for(int gl=0;gl<GPB;gl++) acc[gl]=bj;
        for(int k=0;k<RD+10;k++){
            float wv = w[k*H1+j];
            #pragma unroll
            for(int gl=0;gl<GPB;gl++) acc[gl] += sH[gl][k]*wv;
        }
        int ng = min(GPB, N_GRAPHS-g0);
        float psum=0.f, psq=0.f;
        for(int gl=0;gl<ng;gl++){
            z1[(size_t)(g0+gl)*H1+j]=acc[gl];
            psum+=acc[gl]; psq+=acc[gl]*acc[gl];
        }
        ps[blockIdx.x*H1+j]=psum;
        pq[blockIdx.x*H1+j]=psq;
    }
}

// ---------------- BN finalize: a = g/sqrt(var+eps), c = b - a*mu ----------------
__global__ __launch_bounds__(256) void k_bnfin(const float* __restrict__ ps, const float* __restrict__ pq,
    int nb, int H, const float* __restrict__ gamma, const float* __restrict__ beta,
    float* __restrict__ a, float* __restrict__ c){
    int j = blockIdx.x;
    int t = threadIdx.x;
    float s=0.f, q=0.f;
    for(int i=t;i<nb;i+=256){ s+=ps[(size_t)i*H+j]; q+=pq[(size_t)i*H+j]; }
    __shared__ float sh1[256], sh2[256];
    sh1[t]=s; sh2[t]=q; __syncthreads();
    for(int off=128;off>0;off>>=1){
        if(t<off){ sh1[t]+=sh1[t+off]; sh2[t]+=sh2[t+off]; }
        __syncthreads();
    }
    if(t==0){
        float mean = sh1[0]/(float)N_GRAPHS;
        float var  = sh2[0]/(float)N_GRAPHS - mean*mean;
        float inv  = 1.0f/sqrtf(var + 1e-5f);
        float aj = gamma[j]*inv;
        a[j]=aj; c[j]=beta[j]-aj*mean;
    }
}

// ---------------- fc2: z2 = relu(bn1(z1)) @ w + b, + BN partial stats ----------------
__global__ __launch_bounds__(64) void k_fc2(const float* __restrict__ z1, const float* __restrict__ a1,
    const float* __restrict__ c1, const float* __restrict__ w, const float* __restrict__ b,
    float* __restrict__ z2, float* __restrict__ ps, float* __restrict__ pq){
    __shared__ float sH[GPB][H1];
    int t = threadIdx.x;
    int g0 = blockIdx.x*GPB;
    for(int i=t;i<GPB*H1;i+=64){
        int gl=i/H1, k=i-gl*H1;
        int g=g0+gl;
        float v=0.f;
        if(g<N_GRAPHS){ float z=z1[(size_t)g*H1+k]; v=fmaxf(a1[k]*z+c1[k],0.f); }
        sH[gl][k]=v;
    }
    __syncthreads();
    int j = t;
    if(j < H2){
        float acc[GPB]; float bj=b[j];
        #pragma unroll
        for(int gl=0;gl<GPB;gl++) acc[gl]=bj;
        for(int k=0;k<H1;k++){
            float wv=w[k*H2+j];
            #pragma unroll
            for(int gl=0;gl<GPB;gl++) acc[gl]+=sH[gl][k]*wv;
        }
        int ng=min(GPB,N_GRAPHS-g0);
        float psum=0.f,psq=0.f;
        for(int gl=0;gl<ng;gl++){
            z2[(size_t)(g0+gl)*H2+j]=acc[gl];
            psum+=acc[gl]; psq+=acc[gl]*acc[gl];
        }
        ps[blockIdx.x*H2+j]=psum; pq[blockIdx.x*H2+j]=psq;
    }
}

// ---------------- out: sigmoid(relu(bn2(z2)) @ w + b) ----------------
__global__ __launch_bounds__(192) void k_out(const float* __restrict__ z2, const float* __restrict__ a2,
    const float* __restrict__ c2, const float* __restrict__ w, const float* __restrict__ b,
    float* __restrict__ out){
    __shared__ float sH[GPB][H2];
    int t = threadIdx.x;
    int g0 = blockIdx.x*GPB;
    for(int i=t;i<GPB*H2;i+=192){
        int gl=i/H2, k=i-gl*H2;
        int g=g0+gl;
        float v=0.f;
        if(g<N_GRAPHS){ float z=z2[(size_t)g*H2+k]; v=fmaxf(a2[k]*z+c2[k],0.f); }
        sH[gl][k]=v;
    }
    __syncthreads();
    int j = t;
    if(j < NT){
        float acc[GPB]; float bj=b[j];
        #pragma unroll
        for(int gl=0;gl<GPB;gl++) acc[gl]=bj;
        for(int k=0;k<H2;k++){
            float wv=w[k*NT+j];
            #pragma unroll
            for(int gl=0;gl<GPB;gl++) acc[gl]+=sH[gl][k]*wv;
        }
        int ng=min(GPB,N_GRAPHS-g0);
        for(int gl=0;gl<ng;gl++)
            out[(size_t)(g0+gl)*NT+j] = 1.0f/(1.0f+__expf(-acc[gl]));
    }
}

// ---------------- launcher ----------------
static inline int ceil_div(int a,int b){ return (a+b-1)/b; }

extern "C" void kernel_launch(void* const* d_in, const int* in_sizes, int n_in,
                              void* d_out, int out_size, void* d_ws, size_t ws_size,
                              hipStream_t stream) {
    const float* x     = (const float*)d_in[0];
    const float* mol   = (const float*)d_in[1];
    const int*   ei    = (const int*)  d_in[2];   // [0:E]=src, [E:2E]=dst
    const int*   batch = (const int*)  d_in[3];
    const float* w_g1=(const float*)d_in[4];  const float* b_g1=(const float*)d_in[5];
    const float* w_g2=(const float*)d_in[6];  const float* b_g2=(const float*)d_in[7];
    const float* w_g3=(const float*)d_in[8];  const float* b_g3=(const float*)d_in[9];
    const float* w_g4=(const float*)d_in[10]; const float* b_g4=(const float*)d_in[11];
    const float* w_r1=(const float*)d_in[12]; const float* b_r1=(const float*)d_in[13];
    const float* w_r2=(const float*)d_in[14]; const float* b_r2=(const float*)d_in[15];
    const float* w_r3=(const float*)d_in[16]; const float* b_r3=(const float*)d_in[17];
    const float* w_r4=(const float*)d_in[18]; const float* b_r4=(const float*)d_in[19];
    const float* w_fc1=(const float*)d_in[20]; const float* b_fc1=(const float*)d_in[21];
    const float* bn1_g=(const float*)d_in[22]; const float* bn1_b=(const float*)d_in[23];
    const float* w_fc2=(const float*)d_in[24]; const float* b_fc2=(const float*)d_in[25];
    const float* bn2_g=(const float*)d_in[26]; const float* bn2_b=(const float*)d_in[27];
    const float* w_out=(const float*)d_in[28]; const float* b_out=(const float*)d_in[29];
    float* out = (float*)d_out;

    // workspace carve-up (256B aligned regions)
    char* p = (char*)d_ws;
    auto take=[&](size_t bytes)->char*{ char* q=p; p += (bytes+255)&~(size_t)255; return q; };
    float* y   = (float*)take((size_t)N_NODES*36*4);
    float* xa  = (float*)take((size_t)N_NODES*36*4);
    float* xb  = (float*)take((size_t)N_NODES*36*4);
    int* hist    = (int*)take((size_t)(N_NODES+1)*4);
    int* row_ptr = (int*)take((size_t)(N_NODES+1)*4);
    int* partials= (int*)take(256*4);
    int* bcur    = (int*)take((size_t)NBUCK*4);
    int* packed  = (int*)take((size_t)N_EDGES*4);
    int* csr     = (int*)take((size_t)N_EDGES*4);
    int* gstart  = (int*)take((size_t)N_GRAPHS*4);
    int* gend    = (int*)take((size_t)N_GRAPHS*4);
    float* S  = (float*)take((size_t)N_GRAPHS*SD*4);
    float* r  = (float*)take((size_t)N_GRAPHS*RD*4);
    float* z1 = (float*)take((size_t)N_GRAPHS*H1*4);
    float* z2 = (float*)take((size_t)N_GRAPHS*H2*4);
    const int NB_G = ceil_div(N_GRAPHS, GPB);   // 1563
    float* p1s=(float*)take((size_t)NB_G*H1*4);
    float* p1q=(float*)take((size_t)NB_G*H1*4);
    float* p2s=(float*)take((size_t)NB_G*H2*4);
    float* p2q=(float*)take((size_t)NB_G*H2*4);
    float* a1=(float*)take(H1*4); float* c1=(float*)take(H1*4);
    float* a2=(float*)take(H2*4); float* c2=(float*)take(H2*4);

    const int* src = ei;
    const int* dst = ei + N_EDGES;

    k_init<<<ceil_div(N_NODES+1,256),256,0,stream>>>(hist,gstart,gend);
    k_hist<<<ceil_div(N_EDGES,256),256,0,stream>>>(dst,hist);
    k_scan1<<<NB_SCAN,256,0,stream>>>(hist,partials);
    k_scan2<<<1,256,0,stream>>>(partials);
    k_scan3<<<NB_SCAN,256,0,stream>>>(hist,partials,row_ptr);
    k_binit<<<ceil_div(NBUCK,256),256,0,stream>>>(row_ptr,bcur);
    k_bucket<<<ceil_div(N_EDGES,256),256,0,stream>>>(src,dst,bcur,packed);
    k_scatter2<<<NBUCK,256,0,stream>>>(row_ptr,packed,csr);
    k_bounds<<<ceil_div(N_NODES,256),256,0,stream>>>(batch,gstart,gend);

    // layer 1: x(48) -> y(P=20) -> xa(P=20)
    k_transform<48,20,48,20><<<ceil_div(N_NODES*20,256),256,0,stream>>>(x,w_g1,b_g1,y);
    k_agg<20><<<ceil_div(N_NODES*5,256),256,0,stream>>>((const float4*)y,row_ptr,csr,(float4*)xa);
    k_segsum<20,20><<<N_GRAPHS,64,0,stream>>>(xa,gstart,gend,S,0);
    // layer 2: xa(20) -> y(P=28, D=27) -> xb(P=28)
    k_transform<20,27,20,28><<<ceil_div(N_NODES*28,256),256,0,stream>>>(xa,w_g2,b_g2,y);
    k_agg<28><<<ceil_div(N_NODES*7,256),256,0,stream>>>((const float4*)y,row_ptr,csr,(float4*)xb);
    k_segsum<27,28><<<N_GRAPHS,64,0,stream>>>(xb,gstart,gend,S,20);
    // layer 3: xb(27,P28) -> y(P=36) -> xa(36)
    k_transform<27,36,28,36><<<ceil_div(N_NODES*36,256),256,0,stream>>>(xb,w_g3,b_g3,y);
    k_agg<36><<<ceil_div(N_NODES*9,256),256,0,stream>>>((const float4*)y,row_ptr,csr,(float4*)xa);
    k_segsum<36,36><<<N_GRAPHS,64,0,stream>>>(xa,gstart,gend,S,47);
    // layer 4: xa(36) -> y(P=36) -> xb(36)
    k_transform<36,36,36,36><<<ceil_div(N_NODES*36,256),256,0,stream>>>(xa,w_g4,b_g4,y);
    k_agg<36><<<ceil_div(N_NODES*9,256),256,0,stream>>>((const float4*)y,row_ptr,csr,(float4*)xb);
    k_segsum<36,36><<<N_GRAPHS,64,0,stream>>>(xb,gstart,gend,S,83);

    k_readout<<<NB_G,192,0,stream>>>(S,w_r1,b_r1,w_r2,b_r2,w_r3,b_r3,w_r4,b_r4,r);
    k_fc1<<<NB_G,128,0,stream>>>(r,mol,w_fc1,b_fc1,z1,p1s,p1q);
    k_bnfin<<<H1,256,0,stream>>>(p1s,p1q,NB_G,H1,bn1_g,bn1_b,a1,c1);
    k_fc2<<<NB_G,64,0,stream>>>(z1,a1,c1,w_fc2,b_fc2,z2,p2s,p2q);
    k_bnfin<<<H2,256,0,stream>>>(p2s,p2q,NB_G,H2,bn2_g,bn2_b,a2,c2);
    k_out<<<NB_G,192,0,stream>>>(z2,a2,c2,w_out,b_out,out);
}

// Round 3
// 2190.747 us; speedup vs baseline: 1.5159x; 1.5159x over previous
//
#include <hip/hip_runtime.h>
#include <math.h>

#define N_NODES  500000
#define N_EDGES  8000000
#define N_GRAPHS 25000
#define SD  119   // 20+27+36+36 concatenated segment-sum dim
#define RD  175
#define H1  96
#define H2  63
#define NT  138
#define GPB 16    // graphs per block in dense kernels

#define B2SHIFT 11
#define B2NODES 2048
#define NBUCK2  245          // ceil(500000/2048)
#define BIN_CHUNK 4096
#define NB_BIN 1954          // ceil(8e6/4096)

static __device__ __forceinline__ float selu_f(float m){
    const float scale=1.0507009873554805f, alpha=1.6732632423543772f;
    return m > 0.0f ? scale*m : scale*alpha*(__expf(m)-1.0f);
}

// ---------------- init ----------------
__global__ void k_init(int* chist, int* gstart, int* gend){
    int i = blockIdx.x*256 + threadIdx.x;
    if(i < NBUCK2) chist[i] = 0;
    if(i < N_GRAPHS){ gstart[i]=0; gend[i]=0; }
}

__device__ __forceinline__ int block_excl_scan_256(int v){
    __shared__ int sh[256];
    int t = threadIdx.x;
    sh[t] = v; __syncthreads();
    int acc = v;
    for(int off=1; off<256; off<<=1){
        int add = (t>=off) ? sh[t-off] : 0;
        __syncthreads();
        acc += add;
        sh[t] = acc;
        __syncthreads();
    }
    return acc - v;
}

// ---------------- coarse histogram over dst>>11 ----------------
__global__ __launch_bounds__(256) void k_chist(const int* __restrict__ dst, int* __restrict__ chist){
    __shared__ int lh[256];
    int t = threadIdx.x;
    lh[t]=0; __syncthreads();
    int base = blockIdx.x*BIN_CHUNK;
    #pragma unroll
    for(int k=0;k<16;k++){
        int e = base + k*256 + t;
        if(e < N_EDGES) atomicAdd(&lh[dst[e]>>B2SHIFT], 1);
    }
    __syncthreads();
    if(t < NBUCK2 && lh[t]) atomicAdd(&chist[t], lh[t]);
}

// ---------------- scan coarse hist -> bucket ptrs + cursors ----------------
__global__ void k_cscan(const int* __restrict__ chist, int* __restrict__ cptr, int* __restrict__ bcur){
    int t = threadIdx.x;
    int v = (t<NBUCK2) ? chist[t] : 0;
    int exc = block_excl_scan_256(v);
    if(t <= NBUCK2) cptr[t] = exc;
    if(t <  NBUCK2) bcur[t] = exc;
}

// ---------------- binning pass: LDS-staged, bulk-reserved, coalesced run writes ----------------
__global__ __launch_bounds__(256) void k_bin(const int* __restrict__ src, const int* __restrict__ dst,
                                             int* __restrict__ bcur, int* __restrict__ packed){
    __shared__ int   stage[BIN_CHUNK];
    __shared__ unsigned char bkt[BIN_CHUNK];
    __shared__ int lhist[256], lstart[256], lcur[256], gbase[256];
    int t = threadIdx.x;
    int base = blockIdx.x*BIN_CHUNK;
    int myb[16], mys[16];
    #pragma unroll
    for(int k=0;k<16;k++){
        int e = base + k*256 + t;
        if(e < N_EDGES){
            int d = dst[e];
            myb[k] = d >> B2SHIFT;
            mys[k] = ((d & (B2NODES-1)) << 19) | src[e];
        } else myb[k] = -1;
    }
    lhist[t]=0; __syncthreads();
    #pragma unroll
    for(int k=0;k<16;k++) if(myb[k]>=0) atomicAdd(&lhist[myb[k]],1);
    __syncthreads();
    int v = lhist[t];
    int exc = block_excl_scan_256(v);
    lstart[t]=exc; lcur[t]=exc;
    if(t < NBUCK2 && v>0) gbase[t] = atomicAdd(&bcur[t], v);
    __syncthreads();
    #pragma unroll
    for(int k=0;k<16;k++){
        if(myb[k]>=0){
            int p = atomicAdd(&lcur[myb[k]],1);
            stage[p]=mys[k]; bkt[p]=(unsigned char)myb[k];
        }
    }
    __syncthreads();
    int total = N_EDGES - base; if(total > BIN_CHUNK) total = BIN_CHUNK;
    for(int i=t; i<total; i+=256){
        int b = bkt[i];
        packed[gbase[b] + (i - lstart[b])] = stage[i];
    }
}

// ---------------- fine scatter per 2048-node bucket: fused hist+scan(row_ptr)+scatter ----------------
__global__ __launch_bounds__(1024) void k_scatfine(const int* __restrict__ cptr,
                          const int* __restrict__ packed, int* __restrict__ row_ptr,
                          int* __restrict__ csr){
    __shared__ int cnt[B2NODES];
    __shared__ int sb[1024];
    int t = threadIdx.x;
    int b = blockIdx.x;
    int nb = b << B2SHIFT;
    cnt[t]=0; cnt[t+1024]=0;
    __syncthreads();
    int ebeg = cptr[b], eend = cptr[b+1];
    for(int e=ebeg+t; e<eend; e+=1024){
        int dl = packed[e] >> 19;
        atomicAdd(&cnt[dl],1);
    }
    __syncthreads();
    int c0 = cnt[2*t], c1 = cnt[2*t+1];
    int s = c0+c1;
    sb[t]=s; __syncthreads();
    for(int off=1; off<1024; off<<=1){
        int add = (t>=off) ? sb[t-off] : 0;
        __syncthreads();
        sb[t] += add;
        __syncthreads();
    }
    int excl = sb[t] - s;        // exclusive over pairs
    int e0 = excl, e1 = excl + c0;
    __syncthreads();             // all reads of cnt done
    cnt[2*t]=e0; cnt[2*t+1]=e1;
    int n0 = nb + 2*t, n1 = nb + 2*t + 1;
    if(n0 < N_NODES) row_ptr[n0] = ebeg + e0;
    if(n1 < N_NODES) row_ptr[n1] = ebeg + e1;
    if(b == NBUCK2-1 && t == 0) row_ptr[N_NODES] = N_EDGES;
    __syncthreads();
    for(int e=ebeg+t; e<eend; e+=1024){
        int v = packed[e];
        int dl = v >> 19;
        int pos = ebeg + atomicAdd(&cnt[dl],1);
        csr[pos] = v & 0x7FFFF;
    }
}

// ---------------- graph boundaries (batch is sorted) ----------------
__global__ void k_bounds(const int* __restrict__ batch, int* __restrict__ gstart, int* __restrict__ gend){
    int n = blockIdx.x*256 + threadIdx.x;
    if(n >= N_NODES) return;
    int b = batch[n];
    if(n==0        || batch[n-1]!=b) gstart[b]=n;
    if(n==N_NODES-1|| batch[n+1]!=b) gend[b]=n+1;
}

// ---------------- node transform: y[n][o] = x[n][:DIN] @ W + b, padded-out stride POUT ----------------
template<int DIN,int DOUT,int PIN,int POUT>
__global__ __launch_bounds__(256) void k_transform(const float* __restrict__ x, const float* __restrict__ W,
                                                   const float* __restrict__ bias, float* __restrict__ y){
    __shared__ float sw[DIN*DOUT];
    __shared__ float sb[DOUT];
    int t = threadIdx.x;
    for(int i=t;i<DIN*DOUT;i+=256) sw[i]=W[i];
    if(t<DOUT) sb[t]=bias[t];
    __syncthreads();
    int gid = blockIdx.x*256 + t;
    if(gid >= N_NODES*POUT) return;
    int n = gid/POUT, o = gid - n*POUT;
    if(o >= DOUT){ y[gid]=0.f; return; }   // zero pad lanes
    const float* xr = x + (size_t)n*PIN;
    float acc = sb[o];
    #pragma unroll
    for(int i=0;i<DIN;i++) acc = fmaf(xr[i], sw[i*DOUT+o], acc);
    y[gid]=acc;
}

// ---------------- aggregate (float4 gathers): xo[n][f] = selu(finite(max over in-edges)) ----------------
template<int P>   // P = padded dim, multiple of 4; FG = P/4 float4-groups per node
__global__ __launch_bounds__(256) void k_agg(const float4* __restrict__ y, const int* __restrict__ row_ptr,
                                             const int* __restrict__ csr, float4* __restrict__ xo){
    const int FG = P/4;
    int gid = blockIdx.x*256 + threadIdx.x;
    if(gid >= N_NODES*FG) return;
    int n = gid/FG, fg = gid - n*FG;
    int beg = row_ptr[n], end = row_ptr[n+1];
    float4 m = make_float4(-INFINITY,-INFINITY,-INFINITY,-INFINITY);
    int j = beg;
    for(; j+4<=end; j+=4){
        int s0=csr[j], s1=csr[j+1], s2=csr[j+2], s3=csr[j+3];
        float4 v0=y[(size_t)s0*FG+fg], v1=y[(size_t)s1*FG+fg];
        float4 v2=y[(size_t)s2*FG+fg], v3=y[(size_t)s3*FG+fg];
        m.x = fmaxf(m.x, fmaxf(fmaxf(v0.x,v1.x), fmaxf(v2.x,v3.x)));
        m.y = fmaxf(m.y, fmaxf(fmaxf(v0.y,v1.y), fmaxf(v2.y,v3.y)));
        m.z = fmaxf(m.z, fmaxf(fmaxf(v0.z,v1.z), fmaxf(v2.z,v3.z)));
        m.w = fmaxf(m.w, fmaxf(fmaxf(v0.w,v1.w), fmaxf(v2.w,v3.w)));
    }
    for(; j<end; j++){
        float4 v = y[(size_t)csr[j]*FG+fg];
        m.x=fmaxf(m.x,v.x); m.y=fmaxf(m.y,v.y); m.z=fmaxf(m.z,v.z); m.w=fmaxf(m.w,v.w);
    }
    if(!isfinite(m.x)) m.x=0.f;
    if(!isfinite(m.y)) m.y=0.f;
    if(!isfinite(m.z)) m.z=0.f;
    if(!isfinite(m.w)) m.w=0.f;
    float4 o;
    o.x=selu_f(m.x); o.y=selu_f(m.y); o.z=selu_f(m.z); o.w=selu_f(m.w);
    xo[gid]=o;
}

// ---------------- per-graph segment sum into S[:, off:off+D], input stride P ----------------
template<int D,int P>
__global__ void k_segsum(const float* __restrict__ x, const int* __restrict__ gs, const int* __restrict__ ge,
                         float* __restrict__ S, int off){
    int g = blockIdx.x; int f = threadIdx.x;
    if(f >= D) return;
    int b = gs[g], e = ge[g];
    float acc = 0.f;
    for(int n=b;n<e;n++) acc += x[(size_t)n*P+f];
    S[(size_t)g*SD + off + f] = acc;
}

// ---------------- readout: r = S @ Wcat + sum(b) ----------------
__global__ __launch_bounds__(192) void k_readout(const float* __restrict__ S,
    const float* __restrict__ w1,const float* __restrict__ b1,
    const float* __restrict__ w2,const float* __restrict__ b2,
    const float* __restrict__ w3,const float* __restrict__ b3,
    const float* __restrict__ w4,const float* __restrict__ b4,
    float* __restrict__ r){
    __shared__ float sH[GPB][SD];
    int t = threadIdx.x;
    int g0 = blockIdx.x*GPB;
    for(int i=t;i<GPB*SD;i+=192){
        int gl=i/SD, k=i-gl*SD;
        int g=g0+gl;
        sH[gl][k] = (g<N_GRAPHS) ? S[(size_t)g*SD+k] : 0.f;
    }
    __syncthreads();
    int j = t;
    if(j < RD){
        float acc[GPB];
        float bj = b1[j]+b2[j]+b3[j]+b4[j];
        #pragma unroll
        for(int gl=0;gl<GPB;gl++) acc[gl]=bj;
        for(int k=0;k<20;k++){ float wv=w1[k*RD+j];
            #pragma unroll
            for(int gl=0;gl<GPB;gl++) acc[gl] += sH[gl][k]*wv; }
        for(int k=0;k<27;k++){ float wv=w2[k*RD+j];
            #pragma unroll
            for(int gl=0;gl<GPB;gl++) acc[gl] += sH[gl][20+k]*wv; }
        for(int k=0;k<36;k++){ float wv=w3[k*RD+j];
            #pragma unroll
            for(int gl=0;gl<GPB;gl++) acc[gl] += sH[gl][47+k]*wv; }
        for(int k=0;k<36;k++){ float wv=w4[k*RD+j];
            #pragma unroll
            for(int gl=0;gl<GPB;gl++) acc[gl] += sH[gl][83+k]*wv; }
        int ng = min(GPB, N_GRAPHS-g0);
        for(int gl=0;gl<ng;gl++) r[(size_t)(g0+gl)*RD+j] = acc[gl];
    }
}

// ---------------- fc1: z1 = [r, mol] @ w + b, + BN partial stats ----------------
__global__ __launch_bounds__(128) void k_fc1(const float* __restrict__ r, const float* __restrict__ mol,
    const float* __restrict__ w, const float* __restrict__ b,
    float* __restrict__ z1, float* __restrict__ ps, float* __restrict__ pq){
    __shared__ float sH[GPB][RD+10];
    int t = threadIdx.x;
    int g0 = blockIdx.x*GPB;
    for(int i=t;i<GPB*(RD+10);i+=128){
        int gl=i/(RD+10), k=i-gl*(RD+10);
        int g=g0+gl;
        float v=0.f;
        if(g<N_GRAPHS) v = (k<RD) ? r[(size_t)g*RD+k] : mol[(size_t)g*10 + (k-RD)];
        sH[gl][k]=v;
    }
    __syncthreads();
    int j = t;
    if(j < H1){
        float acc[GPB]; float bj=b[j];
        #pragma unroll
        for(int gl=0;gl<GPB;gl++) acc[gl]=bj;
        for(int k=0;k<RD+10;k++){
            float wv = w[k*H1+j];
            #pragma unroll
            for(int gl=0;gl<GPB;gl++) acc[gl] += sH[gl][k]*wv;
        }
        int ng = min(GPB, N_GRAPHS-g0);
        float psum=0.f, psq=0.f;
        for(int gl=0;gl<ng;gl++){
            z1[(size_t)(g0+gl)*H1+j]=acc[gl];
            psum+=acc[gl]; psq+=acc[gl]*acc[gl];
        }
        ps[blockIdx.x*H1+j]=psum;
        pq[blockIdx.x*H1+j]=psq;
    }
}

// ---------------- BN finalize: a = g/sqrt(var+eps), c = b - a*mu ----------------
__global__ __launch_bounds__(256) void k_bnfin(const float* __restrict__ ps, const float* __restrict__ pq,
    int nb, int H, const float* __restrict__ gamma, const float* __restrict__ beta,
    float* __restrict__ a, float* __restrict__ c){
    int j = blockIdx.x;
    int t = threadIdx.x;
    float s=0.f, q=0.f;
    for(int i=t;i<nb;i+=256){ s+=ps[(size_t)i*H+j]; q+=pq[(size_t)i*H+j]; }
    __shared__ float sh1[256], sh2[256];
    sh1[t]=s; sh2[t]=q; __syncthreads();
    for(int off=128;off>0;off>>=1){
        if(t<off){ sh1[t]+=sh1[t+off]; sh2[t]+=sh2[t+off]; }
        __syncthreads();
    }
    if(t==0){
        float mean = sh1[0]/(float)N_GRAPHS;
        float var  = sh2[0]/(float)N_GRAPHS - mean*mean;
        float inv  = 1.0f/sqrtf(var + 1e-5f);
        float aj = gamma[j]*inv;
        a[j]=aj; c[j]=beta[j]-aj*mean;
    }
}

// ---------------- fc2: z2 = relu(bn1(z1)) @ w + b, + BN partial stats ----------------
__global__ __launch_bounds__(64) void k_fc2(const float* __restrict__ z1, const float* __restrict__ a1,
    const float* __restrict__ c1, const float* __restrict__ w, const float* __restrict__ b,
    float* __restrict__ z2, float* __restrict__ ps, float* __restrict__ pq){
    __shared__ float sH[GPB][H1];
    int t = threadIdx.x;
    int g0 = blockIdx.x*GPB;
    for(int i=t;i<GPB*H1;i+=64){
        int gl=i/H1, k=i-gl*H1;
        int g=g0+gl;
        float v=0.f;
        if(g<N_GRAPHS){ float z=z1[(size_t)g*H1+k]; v=fmaxf(a1[k]*z+c1[k],0.f); }
        sH[gl][k]=v;
    }
    __syncthreads();
    int j = t;
    if(j < H2){
        float acc[GPB]; float bj=b[j];
        #pragma unroll
        for(int gl=0;gl<GPB;gl++) acc[gl]=bj;
        for(int k=0;k<H1;k++){
            float wv=w[k*H2+j];
            #pragma unroll
            for(int gl=0;gl<GPB;gl++) acc[gl]+=sH[gl][k]*wv;
        }
        int ng=min(GPB,N_GRAPHS-g0);
        float psum=0.f,psq=0.f;
        for(int gl=0;gl<ng;gl++){
            z2[(size_t)(g0+gl)*H2+j]=acc[gl];
            psum+=acc[gl]; psq+=acc[gl]*acc[gl];
        }
        ps[blockIdx.x*H2+j]=psum; pq[blockIdx.x*H2+j]=psq;
    }
}

// ---------------- out: sigmoid(relu(bn2(z2)) @ w + b) ----------------
__global__ __launch_bounds__(192) void k_out(const float* __restrict__ z2, const float* __restrict__ a2,
    const float* __restrict__ c2, const float* __restrict__ w, const float* __restrict__ b,
    float* __restrict__ out){
    __shared__ float sH[GPB][H2];
    int t = threadIdx.x;
    int g0 = blockIdx.x*GPB;
    for(int i=t;i<GPB*H2;i+=192){
        int gl=i/H2, k=i-gl*H2;
        int g=g0+gl;
        float v=0.f;
        if(g<N_GRAPHS){ float z=z2[(size_t)g*H2+k]; v=fmaxf(a2[k]*z+c2[k],0.f); }
        sH[gl][k]=v;
    }
    __syncthreads();
    int j = t;
    if(j < NT){
        float acc[GPB]; float bj=b[j];
        #pragma unroll
        for(int gl=0;gl<GPB;gl++) acc[gl]=bj;
        for(int k=0;k<H2;k++){
            float wv=w[k*NT+j];
            #pragma unroll
            for(int gl=0;gl<GPB;gl++) acc[gl]+=sH[gl][k]*wv;
        }
        int ng=min(GPB,N_GRAPHS-g0);
        for(int gl=0;gl<ng;gl++)
            out[(size_t)(g0+gl)*NT+j] = 1.0f/(1.0f+__expf(-acc[gl]));
    }
}

// ---------------- launcher ----------------
static inline int ceil_div(int a,int b){ return (a+b-1)/b; }

extern "C" void kernel_launch(void* const* d_in, const int* in_sizes, int n_in,
                              void* d_out, int out_size, void* d_ws, size_t ws_size,
                              hipStream_t stream) {
    const float* x     = (const float*)d_in[0];
    const float* mol   = (const float*)d_in[1];
    const int*   ei    = (const int*)  d_in[2];   // [0:E]=src, [E:2E]=dst
    const int*   batch = (const int*)  d_in[3];
    const float* w_g1=(const float*)d_in[4];  const float* b_g1=(const float*)d_in[5];
    const float* w_g2=(const float*)d_in[6];  const float* b_g2=(const float*)d_in[7];
    const float* w_g3=(const float*)d_in[8];  const float* b_g3=(const float*)d_in[9];
    const float* w_g4=(const float*)d_in[10]; const float* b_g4=(const float*)d_in[11];
    const float* w_r1=(const float*)d_in[12]; const float* b_r1=(const float*)d_in[13];
    const float* w_r2=(const float*)d_in[14]; const float* b_r2=(const float*)d_in[15];
    const float* w_r3=(const float*)d_in[16]; const float* b_r3=(const float*)d_in[17];
    const float* w_r4=(const float*)d_in[18]; const float* b_r4=(const float*)d_in[19];
    const float* w_fc1=(const float*)d_in[20]; const float* b_fc1=(const float*)d_in[21];
    const float* bn1_g=(const float*)d_in[22]; const float* bn1_b=(const float*)d_in[23];
    const float* w_fc2=(const float*)d_in[24]; const float* b_fc2=(const float*)d_in[25];
    const float* bn2_g=(const float*)d_in[26]; const float* bn2_b=(const float*)d_in[27];
    const float* w_out=(const float*)d_in[28]; const float* b_out=(const float*)d_in[29];
    float* out = (float*)d_out;

    // workspace carve-up (256B aligned regions)
    char* p = (char*)d_ws;
    auto take=[&](size_t bytes)->char*{ char* q=p; p += (bytes+255)&~(size_t)255; return q; };
    float* y   = (float*)take((size_t)N_NODES*36*4);
    float* xa  = (float*)take((size_t)N_NODES*36*4);
    float* xb  = (float*)take((size_t)N_NODES*36*4);
    int* chist   = (int*)take((size_t)NBUCK2*4);
    int* cptr    = (int*)take((size_t)(NBUCK2+1)*4);
    int* bcur    = (int*)take((size_t)NBUCK2*4);
    int* row_ptr = (int*)take((size_t)(N_NODES+1)*4);
    int* packed  = (int*)take((size_t)N_EDGES*4);
    int* csr     = (int*)take((size_t)N_EDGES*4);
    int* gstart  = (int*)take((size_t)N_GRAPHS*4);
    int* gend    = (int*)take((size_t)N_GRAPHS*4);
    float* S  = (float*)take((size_t)N_GRAPHS*SD*4);
    float* r  = (float*)take((size_t)N_GRAPHS*RD*4);
    float* z1 = (float*)take((size_t)N_GRAPHS*H1*4);
    float* z2 = (float*)take((size_t)N_GRAPHS*H2*4);
    const int NB_G = ceil_div(N_GRAPHS, GPB);   // 1563
    float* p1s=(float*)take((size_t)NB_G*H1*4);
    float* p1q=(float*)take((size_t)NB_G*H1*4);
    float* p2s=(float*)take((size_t)NB_G*H2*4);
    float* p2q=(float*)take((size_t)NB_G*H2*4);
    float* a1=(float*)take(H1*4); float* c1=(float*)take(H1*4);
    float* a2=(float*)take(H2*4); float* c2=(float*)take(H2*4);

    const int* src = ei;
    const int* dst = ei + N_EDGES;

    // ---- CSR build: coarse-bin (LDS staged) + fused fine hist/scan/scatter ----
    k_init<<<ceil_div(N_GRAPHS,256),256,0,stream>>>(chist,gstart,gend);
    k_chist<<<NB_BIN,256,0,stream>>>(dst,chist);
    k_cscan<<<1,256,0,stream>>>(chist,cptr,bcur);
    k_bin<<<NB_BIN,256,0,stream>>>(src,dst,bcur,packed);
    k_scatfine<<<NBUCK2,1024,0,stream>>>(cptr,packed,row_ptr,csr);
    k_bounds<<<ceil_div(N_NODES,256),256,0,stream>>>(batch,gstart,gend);

    // layer 1: x(48) -> y(P=20) -> xa(P=20)
    k_transform<48,20,48,20><<<ceil_div(N_NODES*20,256),256,0,stream>>>(x,w_g1,b_g1,y);
    k_agg<20><<<ceil_div(N_NODES*5,256),256,0,stream>>>((const float4*)y,row_ptr,csr,(float4*)xa);
    k_segsum<20,20><<<N_GRAPHS,64,0,stream>>>(xa,gstart,gend,S,0);
    // layer 2: xa(20) -> y(P=28, D=27) -> xb(P=28)
    k_transform<20,27,20,28><<<ceil_div(N_NODES*28,256),256,0,stream>>>(xa,w_g2,b_g2,y);
    k_agg<28><<<ceil_div(N_NODES*7,256),256,0,stream>>>((const float4*)y,row_ptr,csr,(float4*)xb);
    k_segsum<27,28><<<N_GRAPHS,64,0,stream>>>(xb,gstart,gend,S,20);
    // layer 3: xb(27,P28) -> y(P=36) -> xa(36)
    k_transform<27,36,28,36><<<ceil_div(N_NODES*36,256),256,0,stream>>>(xb,w_g3,b_g3,y);
    k_agg<36><<<ceil_div(N_NODES*9,256),256,0,stream>>>((const float4*)y,row_ptr,csr,(float4*)xa);
    k_segsum<36,36><<<N_GRAPHS,64,0,stream>>>(xa,gstart,gend,S,47);
    // layer 4: xa(36) -> y(P=36) -> xb(36)
    k_transform<36,36,36,36><<<ceil_div(N_NODES*36,256),256,0,stream>>>(xa,w_g4,b_g4,y);
    k_agg<36><<<ceil_div(N_NODES*9,256),256,0,stream>>>((const float4*)y,row_ptr,csr,(float4*)xb);
    k_segsum<36,36><<<N_GRAPHS,64,0,stream>>>(xb,gstart,gend,S,83);

    k_readout<<<NB_G,192,0,stream>>>(S,w_r1,b_r1,w_r2,b_r2,w_r3,b_r3,w_r4,b_r4,r);
    k_fc1<<<NB_G,128,0,stream>>>(r,mol,w_fc1,b_fc1,z1,p1s,p1q);
    k_bnfin<<<H1,256,0,stream>>>(p1s,p1q,NB_G,H1,bn1_g,bn1_b,a1,c1);
    k_fc2<<<NB_G,64,0,stream>>>(z1,a1,c1,w_fc2,b_fc2,z2,p2s,p2q);
    k_bnfin<<<H2,256,0,stream>>>(p2s,p2q,NB_G,H2,bn2_g,bn2_b,a2,c2);
    k_out<<<NB_G,192,0,stream>>>(z2,a2,c2,w_out,b_out,out);
}

// Round 6
// 1801.832 us; speedup vs baseline: 1.8431x; 1.2158x over previous
//
#include <hip/hip_runtime.h>
#include <hip/hip_fp16.h>
#include <math.h>

#define N_NODES  500000
#define N_EDGES  8000000
#define N_GRAPHS 25000
#define SD  119   // 20+27+36+36 concatenated segment-sum dim
#define RD  175
#define H1  96
#define H2  63
#define NT  138
#define GPB 16    // graphs per block in dense kernels

#define B2SHIFT 11
#define B2NODES 2048
#define NBUCK2  245          // ceil(500000/2048)
#define BIN_CHUNK 4096
#define NB_BIN 1954          // ceil(8e6/4096)

static __device__ __forceinline__ float selu_f(float m){
    const float scale=1.0507009873554805f, alpha=1.6732632423543772f;
    return m > 0.0f ? scale*m : scale*alpha*(__expf(m)-1.0f);
}

// packed fp16 max on raw 32-bit words (v_pk_max_f16, VOP3P, gfx950)
static __device__ __forceinline__ unsigned pkmax(unsigned a, unsigned b){
    unsigned r;
    asm volatile("v_pk_max_f16 %0, %1, %2" : "=v"(r) : "v"(a), "v"(b));
    return r;
}

static __device__ __forceinline__ float2 h2_to_f2(unsigned u){
    union{ unsigned u; __half2 h; } c; c.u = u;
    return __half22float2(c.h);
}

// ---------------- init ----------------
__global__ void k_init(int* chist, int* gstart, int* gend){
    int i = blockIdx.x*256 + threadIdx.x;
    if(i < NBUCK2) chist[i] = 0;
    if(i < N_GRAPHS){ gstart[i]=0; gend[i]=0; }
}

__device__ __forceinline__ int block_excl_scan_256(int v){
    __shared__ int sh[256];
    int t = threadIdx.x;
    sh[t] = v; __syncthreads();
    int acc = v;
    for(int off=1; off<256; off<<=1){
        int add = (t>=off) ? sh[t-off] : 0;
        __syncthreads();
        acc += add;
        sh[t] = acc;
        __syncthreads();
    }
    return acc - v;
}

// ---------------- coarse histogram over dst>>11 ----------------
__global__ __launch_bounds__(256) void k_chist(const int* __restrict__ dst, int* __restrict__ chist){
    __shared__ int lh[256];
    int t = threadIdx.x;
    lh[t]=0; __syncthreads();
    int base = blockIdx.x*BIN_CHUNK;
    #pragma unroll
    for(int k=0;k<16;k++){
        int e = base + k*256 + t;
        if(e < N_EDGES) atomicAdd(&lh[dst[e]>>B2SHIFT], 1);
    }
    __syncthreads();
    if(t < NBUCK2 && lh[t]) atomicAdd(&chist[t], lh[t]);
}

// ---------------- scan coarse hist -> bucket ptrs + cursors ----------------
__global__ void k_cscan(const int* __restrict__ chist, int* __restrict__ cptr, int* __restrict__ bcur){
    int t = threadIdx.x;
    int v = (t<NBUCK2) ? chist[t] : 0;
    int exc = block_excl_scan_256(v);
    if(t <= NBUCK2) cptr[t] = exc;
    if(t <  NBUCK2) bcur[t] = exc;
}

// ---------------- binning pass: LDS-staged, bulk-reserved, coalesced run writes ----------------
__global__ __launch_bounds__(256) void k_bin(const int* __restrict__ src, const int* __restrict__ dst,
                                             int* __restrict__ bcur, int* __restrict__ packed){
    __shared__ int   stage[BIN_CHUNK];
    __shared__ unsigned char bkt[BIN_CHUNK];
    __shared__ int lhist[256], lstart[256], lcur[256], gbase[256];
    int t = threadIdx.x;
    int base = blockIdx.x*BIN_CHUNK;
    int myb[16], mys[16];
    #pragma unroll
    for(int k=0;k<16;k++){
        int e = base + k*256 + t;
        if(e < N_EDGES){
            int d = dst[e];
            myb[k] = d >> B2SHIFT;
            mys[k] = ((d & (B2NODES-1)) << 19) | src[e];
        } else myb[k] = -1;
    }
    lhist[t]=0; __syncthreads();
    #pragma unroll
    for(int k=0;k<16;k++) if(myb[k]>=0) atomicAdd(&lhist[myb[k]],1);
    __syncthreads();
    int v = lhist[t];
    int exc = block_excl_scan_256(v);
    lstart[t]=exc; lcur[t]=exc;
    if(t < NBUCK2 && v>0) gbase[t] = atomicAdd(&bcur[t], v);
    __syncthreads();
    #pragma unroll
    for(int k=0;k<16;k++){
        if(myb[k]>=0){
            int p = atomicAdd(&lcur[myb[k]],1);
            stage[p]=mys[k]; bkt[p]=(unsigned char)myb[k];
        }
    }
    __syncthreads();
    int total = N_EDGES - base; if(total > BIN_CHUNK) total = BIN_CHUNK;
    for(int i=t; i<total; i+=256){
        int b = bkt[i];
        packed[gbase[b] + (i - lstart[b])] = stage[i];
    }
}

// ---------------- fine scatter per 2048-node bucket: fused hist+scan(row_ptr)+scatter ----------------
__global__ __launch_bounds__(1024) void k_scatfine(const int* __restrict__ cptr,
                          const int* __restrict__ packed, int* __restrict__ row_ptr,
                          int* __restrict__ csr){
    __shared__ int cnt[B2NODES];
    __shared__ int sb[1024];
    int t = threadIdx.x;
    int b = blockIdx.x;
    int nb = b << B2SHIFT;
    cnt[t]=0; cnt[t+1024]=0;
    __syncthreads();
    int ebeg = cptr[b], eend = cptr[b+1];
    for(int e=ebeg+t; e<eend; e+=1024){
        int dl = packed[e] >> 19;
        atomicAdd(&cnt[dl],1);
    }
    __syncthreads();
    int c0 = cnt[2*t], c1 = cnt[2*t+1];
    int s = c0+c1;
    sb[t]=s; __syncthreads();
    for(int off=1; off<1024; off<<=1){
        int add = (t>=off) ? sb[t-off] : 0;
        __syncthreads();
        sb[t] += add;
        __syncthreads();
    }
    int excl = sb[t] - s;        // exclusive over pairs
    int e0 = excl, e1 = excl + c0;
    __syncthreads();             // all reads of cnt done
    cnt[2*t]=e0; cnt[2*t+1]=e1;
    int n0 = nb + 2*t, n1 = nb + 2*t + 1;
    if(n0 < N_NODES) row_ptr[n0] = ebeg + e0;
    if(n1 < N_NODES) row_ptr[n1] = ebeg + e1;
    if(b == NBUCK2-1 && t == 0) row_ptr[N_NODES] = N_EDGES;
    __syncthreads();
    for(int e=ebeg+t; e<eend; e+=1024){
        int v = packed[e];
        int dl = v >> 19;
        int pos = ebeg + atomicAdd(&cnt[dl],1);
        csr[pos] = v & 0x7FFFF;
    }
}

// ---------------- graph boundaries (batch is sorted) ----------------
__global__ void k_bounds(const int* __restrict__ batch, int* __restrict__ gstart, int* __restrict__ gend){
    int n = blockIdx.x*256 + threadIdx.x;
    if(n >= N_NODES) return;
    int b = batch[n];
    if(n==0        || batch[n-1]!=b) gstart[b]=n;
    if(n==N_NODES-1|| batch[n+1]!=b) gend[b]=n+1;
}

// ---------------- node transform -> fp16 y, padded stride PH ----------------
// x row stride PIN (fp32, pads zero), weights/bias zero-padded into LDS.
template<int DIN,int DOUT,int PIN,int PH>
__global__ __launch_bounds__(256) void k_transform_h(const float* __restrict__ x, const float* __restrict__ W,
                                                     const float* __restrict__ bias, __half* __restrict__ y){
    __shared__ float swp[PIN*PH];
    __shared__ float sbp[PH];
    int t = threadIdx.x;
    for(int i=t;i<PIN*PH;i+=256){
        int row=i/PH, o=i-row*PH;
        swp[i] = (row<DIN && o<DOUT) ? W[row*DOUT+o] : 0.f;
    }
    if(t<PH) sbp[t] = (t<DOUT) ? bias[t] : 0.f;
    __syncthreads();
    const int TPN = PH/2;
    int gid = blockIdx.x*256 + t;
    if(gid >= N_NODES*TPN) return;
    int n = gid/TPN, op = gid - n*TPN;
    int o0 = 2*op, o1 = o0+1;
    const float4* xr4 = (const float4*)(x + (size_t)n*PIN);
    float acc0 = sbp[o0], acc1 = sbp[o1];
    #pragma unroll
    for(int i4=0;i4<PIN/4;i4++){
        float4 xv = xr4[i4];
        acc0 = fmaf(xv.x, swp[(4*i4+0)*PH+o0], acc0);
        acc1 = fmaf(xv.x, swp[(4*i4+0)*PH+o1], acc1);
        acc0 = fmaf(xv.y, swp[(4*i4+1)*PH+o0], acc0);
        acc1 = fmaf(xv.y, swp[(4*i4+1)*PH+o1], acc1);
        acc0 = fmaf(xv.z, swp[(4*i4+2)*PH+o0], acc0);
        acc1 = fmaf(xv.z, swp[(4*i4+2)*PH+o1], acc1);
        acc0 = fmaf(xv.w, swp[(4*i4+3)*PH+o0], acc0);
        acc1 = fmaf(xv.w, swp[(4*i4+3)*PH+o1], acc1);
    }
    __half2* y2 = (__half2*)y;
    y2[((size_t)n*PH>>1) + op] = __floats2half2_rn(acc0, acc1);
}

// ---------------- aggregate (fp16 packed gathers): xo fp32, stride PH ----------------
template<int PH>   // PH multiple of 8; FG = PH/8 uint4-chunks (8 halfs) per node
__global__ __launch_bounds__(256) void k_agg_h(const __half* __restrict__ y, const int* __restrict__ row_ptr,
                                               const int* __restrict__ csr, float* __restrict__ xo){
    const int FG = PH/8;
    int gid = blockIdx.x*256 + threadIdx.x;
    if(gid >= N_NODES*FG) return;
    int n = gid/FG, fg = gid - n*FG;
    const uint4* yv = (const uint4*)y;   // row = FG uint4s
    int beg = row_ptr[n], end = row_ptr[n+1];
    const unsigned NEG2 = 0xFC00FC00u;   // (-inf, -inf) fp16
    unsigned m0=NEG2, m1=NEG2, m2=NEG2, m3=NEG2;
    int j = beg;
    for(; j+4<=end; j+=4){
        int s0=csr[j], s1=csr[j+1], s2=csr[j+2], s3=csr[j+3];
        uint4 v0=yv[s0*FG+fg], v1=yv[s1*FG+fg], v2=yv[s2*FG+fg], v3=yv[s3*FG+fg];
        m0=pkmax(m0,v0.x); m1=pkmax(m1,v0.y); m2=pkmax(m2,v0.z); m3=pkmax(m3,v0.w);
        m0=pkmax(m0,v1.x); m1=pkmax(m1,v1.y); m2=pkmax(m2,v1.z); m3=pkmax(m3,v1.w);
        m0=pkmax(m0,v2.x); m1=pkmax(m1,v2.y); m2=pkmax(m2,v2.z); m3=pkmax(m3,v2.w);
        m0=pkmax(m0,v3.x); m1=pkmax(m1,v3.y); m2=pkmax(m2,v3.z); m3=pkmax(m3,v3.w);
    }
    for(; j<end; j++){
        uint4 v = yv[csr[j]*FG+fg];
        m0=pkmax(m0,v.x); m1=pkmax(m1,v.y); m2=pkmax(m2,v.z); m3=pkmax(m3,v.w);
    }
    float2 f0=h2_to_f2(m0), f1=h2_to_f2(m1), f2=h2_to_f2(m2), f3=h2_to_f2(m3);
    float f[8] = {f0.x,f0.y,f1.x,f1.y,f2.x,f2.y,f3.x,f3.y};
    float o[8];
    #pragma unroll
    for(int k=0;k<8;k++){
        float m = f[k];
        if(m < -1e30f) m = 0.0f;    // empty segment (-inf) -> 0
        o[k] = selu_f(m);
    }
    float4* xov = (float4*)(xo + (size_t)n*PH + 8*fg);
    xov[0] = make_float4(o[0],o[1],o[2],o[3]);
    xov[1] = make_float4(o[4],o[5],o[6],o[7]);
}

// ---------------- per-graph segment sum into S[:, off:off+D], input stride P ----------------
template<int D,int P>
__global__ void k_segsum(const float* __restrict__ x, const int* __restrict__ gs, const int* __restrict__ ge,
                         float* __restrict__ S, int off){
    int g = blockIdx.x; int f = threadIdx.x;
    if(f >= D) return;
    int b = gs[g], e = ge[g];
    float acc = 0.f;
    for(int n=b;n<e;n++) acc += x[(size_t)n*P+f];
    S[(size_t)g*SD + off + f] = acc;
}

// ---------------- readout: r = S @ Wcat + sum(b) ----------------
__global__ __launch_bounds__(192) void k_readout(const float* __restrict__ S,
    const float* __restrict__ w1,const float* __restrict__ b1,
    const float* __restrict__ w2,const float* __restrict__ b2,
    const float* __restrict__ w3,const float* __restrict__ b3,
    const float* __restrict__ w4,const float* __restrict__ b4,
    float* __restrict__ r){
    __shared__ float sH[GPB][SD];
    int t = threadIdx.x;
    int g0 = blockIdx.x*GPB;
    for(int i=t;i<GPB*SD;i+=192){
        int gl=i/SD, k=i-gl*SD;
        int g=g0+gl;
        sH[gl][k] = (g<N_GRAPHS) ? S[(size_t)g*SD+k] : 0.f;
    }
    __syncthreads();
    int j = t;
    if(j < RD){
        float acc[GPB];
        float bj = b1[j]+b2[j]+b3[j]+b4[j];
        #pragma unroll
        for(int gl=0;gl<GPB;gl++) acc[gl]=bj;
        for(int k=0;k<20;k++){ float wv=w1[k*RD+j];
            #pragma unroll
            for(int gl=0;gl<GPB;gl++) acc[gl] += sH[gl][k]*wv; }
        for(int k=0;k<27;k++){ float wv=w2[k*RD+j];
            #pragma unroll
            for(int gl=0;gl<GPB;gl++) acc[gl] += sH[gl][20+k]*wv; }
        for(int k=0;k<36;k++){ float wv=w3[k*RD+j];
            #pragma unroll
            for(int gl=0;gl<GPB;gl++) acc[gl] += sH[gl][47+k]*wv; }
        for(int k=0;k<36;k++){ float wv=w4[k*RD+j];
            #pragma unroll
            for(int gl=0;gl<GPB;gl++) acc[gl] += sH[gl][83+k]*wv; }
        int ng = min(GPB, N_GRAPHS-g0);
        for(int gl=0;gl<ng;gl++) r[(size_t)(g0+gl)*RD+j] = acc[gl];
    }
}

// ---------------- fc1: z1 = [r, mol] @ w + b, + BN partial stats ----------------
__global__ __launch_bounds__(128) void k_fc1(const float* __restrict__ r, const float* __restrict__ mol,
    const float* __restrict__ w, const float* __restrict__ b,
    float* __restrict__ z1, float* __restrict__ ps, float* __restrict__ pq){
    __shared__ float sH[GPB][RD+10];
    int t = threadIdx.x;
    int g0 = blockIdx.x*GPB;
    for(int i=t;i<GPB*(RD+10);i+=128){
        int gl=i/(RD+10), k=i-gl*(RD+10);
        int g=g0+gl;
        float v=0.f;
        if(g<N_GRAPHS) v = (k<RD) ? r[(size_t)g*RD+k] : mol[(size_t)g*10 + (k-RD)];
        sH[gl][k]=v;
    }
    __syncthreads();
    int j = t;
    if(j < H1){
        float acc[GPB]; float bj=b[j];
        #pragma unroll
        for(int gl=0;gl<GPB;gl++) acc[gl]=bj;
        for(int k=0;k<RD+10;k++){
            float wv = w[k*H1+j];
            #pragma unroll
            for(int gl=0;gl<GPB;gl++) acc[gl] += sH[gl][k]*wv;
        }
        int ng = min(GPB, N_GRAPHS-g0);
        float psum=0.f, psq=0.f;
        for(int gl=0;gl<ng;gl++){
            z1[(size_t)(g0+gl)*H1+j]=acc[gl];
            psum+=acc[gl]; psq+=acc[gl]*acc[gl];
        }
        ps[blockIdx.x*H1+j]=psum;
        pq[blockIdx.x*H1+j]=psq;
    }
}

// ---------------- BN finalize: a = g/sqrt(var+eps), c = b - a*mu ----------------
__global__ __launch_bounds__(256) void k_bnfin(const float* __restrict__ ps, const float* __restrict__ pq,
    int nb, int H, const float* __restrict__ gamma, const float* __restrict__ beta,
    float* __restrict__ a, float* __restrict__ c){
    int j = blockIdx.x;
    int t = threadIdx.x;
    float s=0.f, q=0.f;
    for(int i=t;i<nb;i+=256){ s+=ps[(size_t)i*H+j]; q+=pq[(size_t)i*H+j]; }
    __shared__ float sh1[256], sh2[256];
    sh1[t]=s; sh2[t]=q; __syncthreads();
    for(int off=128;off>0;off>>=1){
        if(t<off){ sh1[t]+=sh1[t+off]; sh2[t]+=sh2[t+off]; }
        __syncthreads();
    }
    if(t==0){
        float mean = sh1[0]/(float)N_GRAPHS;
        float var  = sh2[0]/(float)N_GRAPHS - mean*mean;
        float inv  = 1.0f/sqrtf(var + 1e-5f);
        float aj = gamma[j]*inv;
        a[j]=aj; c[j]=beta[j]-aj*mean;
    }
}

// ---------------- fc2: z2 = relu(bn1(z1)) @ w + b, + BN partial stats ----------------
__global__ __launch_bounds__(64) void k_fc2(const float* __restrict__ z1, const float* __restrict__ a1,
    const float* __restrict__ c1, const float* __restrict__ w, const float* __restrict__ b,
    float* __restrict__ z2, float* __restrict__ ps, float* __restrict__ pq){
    __shared__ float sH[GPB][H1];
    int t = threadIdx.x;
    int g0 = blockIdx.x*GPB;
    for(int i=t;i<GPB*H1;i+=64){
        int gl=i/H1, k=i-gl*H1;
        int g=g0+gl;
        float v=0.f;
        if(g<N_GRAPHS){ float z=z1[(size_t)g*H1+k]; v=fmaxf(a1[k]*z+c1[k],0.f); }
        sH[gl][k]=v;
    }
    __syncthreads();
    int j = t;
    if(j < H2){
        float acc[GPB]; float bj=b[j];
        #pragma unroll
        for(int gl=0;gl<GPB;gl++) acc[gl]=bj;
        for(int k=0;k<H1;k++){
            float wv=w[k*H2+j];
            #pragma unroll
            for(int gl=0;gl<GPB;gl++) acc[gl]+=sH[gl][k]*wv;
        }
        int ng=min(GPB,N_GRAPHS-g0);
        float psum=0.f,psq=0.f;
        for(int gl=0;gl<ng;gl++){
            z2[(size_t)(g0+gl)*H2+j]=acc[gl];
            psum+=acc[gl]; psq+=acc[gl]*acc[gl];
        }
        ps[blockIdx.x*H2+j]=psum; pq[blockIdx.x*H2+j]=psq;
    }
}

// ---------------- out: sigmoid(relu(bn2(z2)) @ w + b) ----------------
__global__ __launch_bounds__(192) void k_out(const float* __restrict__ z2, const float* __restrict__ a2,
    const float* __restrict__ c2, const float* __restrict__ w, const float* __restrict__ b,
    float* __restrict__ out){
    __shared__ float sH[GPB][H2];
    int t = threadIdx.x;
    int g0 = blockIdx.x*GPB;
    for(int i=t;i<GPB*H2;i+=192){
        int gl=i/H2, k=i-gl*H2;
        int g=g0+gl;
        float v=0.f;
        if(g<N_GRAPHS){ float z=z2[(size_t)g*H2+k]; v=fmaxf(a2[k]*z+c2[k],0.f); }
        sH[gl][k]=v;
    }
    __syncthreads();
    int j = t;
    if(j < NT){
        float acc[GPB]; float bj=b[j];
        #pragma unroll
        for(int gl=0;gl<GPB;gl++) acc[gl]=bj;
        for(int k=0;k<H2;k++){
            float wv=w[k*NT+j];
            #pragma unroll
            for(int gl=0;gl<GPB;gl++) acc[gl]+=sH[gl][k]*wv;
        }
        int ng=min(GPB,N_GRAPHS-g0);
        for(int gl=0;gl<ng;gl++)
            out[(size_t)(g0+gl)*NT+j] = 1.0f/(1.0f+__expf(-acc[gl]));
    }
}

// ---------------- launcher ----------------
static inline int ceil_div(int a,int b){ return (a+b-1)/b; }

extern "C" void kernel_launch(void* const* d_in, const int* in_sizes, int n_in,
                              void* d_out, int out_size, void* d_ws, size_t ws_size,
                              hipStream_t stream) {
    const float* x     = (const float*)d_in[0];
    const float* mol   = (const float*)d_in[1];
    const int*   ei    = (const int*)  d_in[2];   // [0:E]=src, [E:2E]=dst
    const int*   batch = (const int*)  d_in[3];
    const float* w_g1=(const float*)d_in[4];  const float* b_g1=(const float*)d_in[5];
    const float* w_g2=(const float*)d_in[6];  const float* b_g2=(const float*)d_in[7];
    const float* w_g3=(const float*)d_in[8];  const float* b_g3=(const float*)d_in[9];
    const float* w_g4=(const float*)d_in[10]; const float* b_g4=(const float*)d_in[11];
    const float* w_r1=(const float*)d_in[12]; const float* b_r1=(const float*)d_in[13];
    const float* w_r2=(const float*)d_in[14]; const float* b_r2=(const float*)d_in[15];
    const float* w_r3=(const float*)d_in[16]; const float* b_r3=(const float*)d_in[17];
    const float* w_r4=(const float*)d_in[18]; const float* b_r4=(const float*)d_in[19];
    const float* w_fc1=(const float*)d_in[20]; const float* b_fc1=(const float*)d_in[21];
    const float* bn1_g=(const float*)d_in[22]; const float* bn1_b=(const float*)d_in[23];
    const float* w_fc2=(const float*)d_in[24]; const float* b_fc2=(const float*)d_in[25];
    const float* bn2_g=(const float*)d_in[26]; const float* bn2_b=(const float*)d_in[27];
    const float* w_out=(const float*)d_in[28]; const float* b_out=(const float*)d_in[29];
    float* out = (float*)d_out;

    // workspace carve-up (256B aligned regions)
    char* p = (char*)d_ws;
    auto take=[&](size_t bytes)->char*{ char* q=p; p += (bytes+255)&~(size_t)255; return q; };
    __half* y  = (__half*)take((size_t)N_NODES*40*2);
    float* xa  = (float*)take((size_t)N_NODES*40*4);
    float* xb  = (float*)take((size_t)N_NODES*40*4);
    int* chist   = (int*)take((size_t)NBUCK2*4);
    int* cptr    = (int*)take((size_t)(NBUCK2+1)*4);
    int* bcur    = (int*)take((size_t)NBUCK2*4);
    int* row_ptr = (int*)take((size_t)(N_NODES+1)*4);
    int* packed  = (int*)take((size_t)N_EDGES*4);
    int* csr     = (int*)take((size_t)N_EDGES*4);
    int* gstart  = (int*)take((size_t)N_GRAPHS*4);
    int* gend    = (int*)take((size_t)N_GRAPHS*4);
    float* S  = (float*)take((size_t)N_GRAPHS*SD*4);
    float* r  = (float*)take((size_t)N_GRAPHS*RD*4);
    float* z1 = (float*)take((size_t)N_GRAPHS*H1*4);
    float* z2 = (float*)take((size_t)N_GRAPHS*H2*4);
    const int NB_G = ceil_div(N_GRAPHS, GPB);   // 1563
    float* p1s=(float*)take((size_t)NB_G*H1*4);
    float* p1q=(float*)take((size_t)NB_G*H1*4);
    float* p2s=(float*)take((size_t)NB_G*H2*4);
    float* p2q=(float*)take((size_t)NB_G*H2*4);
    float* a1=(float*)take(H1*4); float* c1=(float*)take(H1*4);
    float* a2=(float*)take(H2*4); float* c2=(float*)take(H2*4);

    const int* src = ei;
    const int* dst = ei + N_EDGES;

    // ---- CSR build: coarse-bin (LDS staged) + fused fine hist/scan/scatter ----
    k_init<<<ceil_div(N_GRAPHS,256),256,0,stream>>>(chist,gstart,gend);
    k_chist<<<NB_BIN,256,0,stream>>>(dst,chist);
    k_cscan<<<1,256,0,stream>>>(chist,cptr,bcur);
    k_bin<<<NB_BIN,256,0,stream>>>(src,dst,bcur,packed);
    k_scatfine<<<NBUCK2,1024,0,stream>>>(cptr,packed,row_ptr,csr);
    k_bounds<<<ceil_div(N_NODES,256),256,0,stream>>>(batch,gstart,gend);

    // layer 1: x(48 fp32) -> y(fp16 PH=24, D=20) -> xa(fp32 stride 24)
    k_transform_h<48,20,48,24><<<ceil_div(N_NODES*12,256),256,0,stream>>>(x,w_g1,b_g1,y);
    k_agg_h<24><<<ceil_div(N_NODES*3,256),256,0,stream>>>(y,row_ptr,csr,xa);
    k_segsum<20,24><<<N_GRAPHS,64,0,stream>>>(xa,gstart,gend,S,0);
    // layer 2: xa(20, stride 24) -> y(fp16 PH=32, D=27) -> xb(stride 32)
    k_transform_h<20,27,24,32><<<ceil_div(N_NODES*16,256),256,0,stream>>>(xa,w_g2,b_g2,y);
    k_agg_h<32><<<ceil_div(N_NODES*4,256),256,0,stream>>>(y,row_ptr,csr,xb);
    k_segsum<27,32><<<N_GRAPHS,64,0,stream>>>(xb,gstart,gend,S,20);
    // layer 3: xb(27, stride 32) -> y(fp16 PH=40, D=36) -> xa(stride 40)
    k_transform_h<27,36,32,40><<<ceil_div(N_NODES*20,256),256,0,stream>>>(xb,w_g3,b_g3,y);
    k_agg_h<40><<<ceil_div(N_NODES*5,256),256,0,stream>>>(y,row_ptr,csr,xa);
    k_segsum<36,40><<<N_GRAPHS,64,0,stream>>>(xa,gstart,gend,S,47);
    // layer 4: xa(36, stride 40) -> y(fp16 PH=40) -> xb(stride 40)
    k_transform_h<36,36,40,40><<<ceil_div(N_NODES*20,256),256,0,stream>>>(xa,w_g4,b_g4,y);
    k_agg_h<40><<<ceil_div(N_NODES*5,256),256,0,stream>>>(y,row_ptr,csr,xb);
    k_segsum<36,40><<<N_GRAPHS,64,0,stream>>>(xb,gstart,gend,S,83);

    k_readout<<<NB_G,192,0,stream>>>(S,w_r1,b_r1,w_r2,b_r2,w_r3,b_r3,w_r4,b_r4,r);
    k_fc1<<<NB_G,128,0,stream>>>(r,mol,w_fc1,b_fc1,z1,p1s,p1q);
    k_bnfin<<<H1,256,0,stream>>>(p1s,p1q,NB_G,H1,bn1_g,bn1_b,a1,c1);
    k_fc2<<<NB_G,64,0,stream>>>(z1,a1,c1,w_fc2,b_fc2,z2,p2s,p2q);
    k_bnfin<<<H2,256,0,stream>>>(p2s,p2q,NB_G,H2,bn2_g,bn2_b,a2,c2);
    k_out<<<NB_G,192,0,stream>>>(z2,a2,c2,w_out,b_out,out);
}

// Round 8
// 1466.626 us; speedup vs baseline: 2.2644x; 1.2286x over previous
//
#include <hip/hip_runtime.h>
#include <hip/hip_fp16.h>
#include <math.h>

#define N_NODES  500000
#define N_EDGES  8000000
#define N_GRAPHS 25000
#define SD  119   // 20+27+36+36 concatenated segment-sum dim
#define RD  175
#define H1  96
#define H2  63
#define NT  138
#define GPB 16    // graphs per block in dense kernels

#define B2SHIFT 11
#define B2NODES 2048
#define NBUCK2  245          // ceil(500000/2048)
#define BIN_CHUNK 4096
#define NB_BIN 1954          // ceil(8e6/4096)
#define NBF 7813             // ceil(500000/64) fused-layer blocks

static __device__ __forceinline__ float selu_f(float m){
    const float scale=1.0507009873554805f, alpha=1.6732632423543772f;
    return m > 0.0f ? scale*m : scale*alpha*(__expf(m)-1.0f);
}

// packed fp16 max on raw 32-bit words (v_pk_max_f16, VOP3P, gfx950)
static __device__ __forceinline__ unsigned pkmax(unsigned a, unsigned b){
    unsigned r;
    asm volatile("v_pk_max_f16 %0, %1, %2" : "=v"(r) : "v"(a), "v"(b));
    return r;
}

static __device__ __forceinline__ float2 h2_to_f2(unsigned u){
    union{ unsigned u; __half2 h; } c; c.u = u;
    return __half22float2(c.h);
}

// ---------------- init: zero chist + S ----------------
__global__ void k_init(int* chist, float* S){
    int i = blockIdx.x*256 + threadIdx.x;
    if(i < NBUCK2) chist[i] = 0;
    if(i < N_GRAPHS*SD) S[i] = 0.f;
}

__device__ __forceinline__ int block_excl_scan_256(int v){
    __shared__ int sh[256];
    int t = threadIdx.x;
    sh[t] = v; __syncthreads();
    int acc = v;
    for(int off=1; off<256; off<<=1){
        int add = (t>=off) ? sh[t-off] : 0;
        __syncthreads();
        acc += add;
        sh[t] = acc;
        __syncthreads();
    }
    return acc - v;
}

// ---------------- coarse histogram over dst>>11 ----------------
__global__ __launch_bounds__(256) void k_chist(const int* __restrict__ dst, int* __restrict__ chist){
    __shared__ int lh[256];
    int t = threadIdx.x;
    lh[t]=0; __syncthreads();
    int base = blockIdx.x*BIN_CHUNK;
    #pragma unroll
    for(int k=0;k<16;k++){
        int e = base + k*256 + t;
        if(e < N_EDGES) atomicAdd(&lh[dst[e]>>B2SHIFT], 1);
    }
    __syncthreads();
    if(t < NBUCK2 && lh[t]) atomicAdd(&chist[t], lh[t]);
}

// ---------------- scan coarse hist -> bucket ptrs + cursors ----------------
__global__ void k_cscan(const int* __restrict__ chist, int* __restrict__ cptr, int* __restrict__ bcur){
    int t = threadIdx.x;
    int v = (t<NBUCK2) ? chist[t] : 0;
    int exc = block_excl_scan_256(v);
    if(t <= NBUCK2) cptr[t] = exc;
    if(t <  NBUCK2) bcur[t] = exc;
}

// ---------------- binning pass: LDS-staged, bulk-reserved, coalesced run writes ----------------
__global__ __launch_bounds__(256) void k_bin(const int* __restrict__ src, const int* __restrict__ dst,
                                             int* __restrict__ bcur, int* __restrict__ packed){
    __shared__ int   stage[BIN_CHUNK];
    __shared__ unsigned char bkt[BIN_CHUNK];
    __shared__ int lhist[256], lstart[256], lcur[256], gbase[256];
    int t = threadIdx.x;
    int base = blockIdx.x*BIN_CHUNK;
    int myb[16], mys[16];
    #pragma unroll
    for(int k=0;k<16;k++){
        int e = base + k*256 + t;
        if(e < N_EDGES){
            int d = dst[e];
            myb[k] = d >> B2SHIFT;
            mys[k] = ((d & (B2NODES-1)) << 19) | src[e];
        } else myb[k] = -1;
    }
    lhist[t]=0; __syncthreads();
    #pragma unroll
    for(int k=0;k<16;k++) if(myb[k]>=0) atomicAdd(&lhist[myb[k]],1);
    __syncthreads();
    int v = lhist[t];
    int exc = block_excl_scan_256(v);
    lstart[t]=exc; lcur[t]=exc;
    if(t < NBUCK2 && v>0) gbase[t] = atomicAdd(&bcur[t], v);
    __syncthreads();
    #pragma unroll
    for(int k=0;k<16;k++){
        if(myb[k]>=0){
            int p = atomicAdd(&lcur[myb[k]],1);
            stage[p]=mys[k]; bkt[p]=(unsigned char)myb[k];
        }
    }
    __syncthreads();
    int total = N_EDGES - base; if(total > BIN_CHUNK) total = BIN_CHUNK;
    for(int i=t; i<total; i+=256){
        int b = bkt[i];
        packed[gbase[b] + (i - lstart[b])] = stage[i];
    }
}

// ---------------- fine scatter per 2048-node bucket: fused hist+scan(row_ptr)+scatter ----------------
__global__ __launch_bounds__(1024) void k_scatfine(const int* __restrict__ cptr,
                          const int* __restrict__ packed, int* __restrict__ row_ptr,
                          int* __restrict__ csr){
    __shared__ int cnt[B2NODES];
    __shared__ int sb[1024];
    int t = threadIdx.x;
    int b = blockIdx.x;
    int nb = b << B2SHIFT;
    cnt[t]=0; cnt[t+1024]=0;
    __syncthreads();
    int ebeg = cptr[b], eend = cptr[b+1];
    for(int e=ebeg+t; e<eend; e+=1024){
        int dl = packed[e] >> 19;
        atomicAdd(&cnt[dl],1);
    }
    __syncthreads();
    int c0 = cnt[2*t], c1 = cnt[2*t+1];
    int s = c0+c1;
    sb[t]=s; __syncthreads();
    for(int off=1; off<1024; off<<=1){
        int add = (t>=off) ? sb[t-off] : 0;
        __syncthreads();
        sb[t] += add;
        __syncthreads();
    }
    int excl = sb[t] - s;        // exclusive over pairs
    int e0 = excl, e1 = excl + c0;
    __syncthreads();             // all reads of cnt done
    cnt[2*t]=e0; cnt[2*t+1]=e1;
    int n0 = nb + 2*t, n1 = nb + 2*t + 1;
    if(n0 < N_NODES) row_ptr[n0] = ebeg + e0;
    if(n1 < N_NODES) row_ptr[n1] = ebeg + e1;
    if(b == NBUCK2-1 && t == 0) row_ptr[N_NODES] = N_EDGES;
    __syncthreads();
    for(int e=ebeg+t; e<eend; e+=1024){
        int v = packed[e];
        int dl = v >> 19;
        int pos = ebeg + atomicAdd(&cnt[dl],1);
        csr[pos] = v & 0x7FFFF;
    }
}

// ---------------- node transform (layer 1 only) -> fp16 y, padded stride PH ----------------
template<int DIN,int DOUT,int PIN,int PH>
__global__ __launch_bounds__(256) void k_transform_h(const float* __restrict__ x, const float* __restrict__ W,
                                                     const float* __restrict__ bias, __half* __restrict__ y){
    __shared__ float swp[PIN*PH];
    __shared__ float sbp[PH];
    int t = threadIdx.x;
    for(int i=t;i<PIN*PH;i+=256){
        int row=i/PH, o=i-row*PH;
        swp[i] = (row<DIN && o<DOUT) ? W[row*DOUT+o] : 0.f;
    }
    if(t<PH) sbp[t] = (t<DOUT) ? bias[t] : 0.f;
    __syncthreads();
    const int TPN = PH/2;
    int gid = blockIdx.x*256 + t;
    if(gid >= N_NODES*TPN) return;
    int n = gid/TPN, op = gid - n*TPN;
    int o0 = 2*op, o1 = o0+1;
    const float4* xr4 = (const float4*)(x + (size_t)n*PIN);
    float acc0 = sbp[o0], acc1 = sbp[o1];
    #pragma unroll
    for(int i4=0;i4<PIN/4;i4++){
        float4 xv = xr4[i4];
        acc0 = fmaf(xv.x, swp[(4*i4+0)*PH+o0], acc0);
        acc1 = fmaf(xv.x, swp[(4*i4+0)*PH+o1], acc1);
        acc0 = fmaf(xv.y, swp[(4*i4+1)*PH+o0], acc0);
        acc1 = fmaf(xv.y, swp[(4*i4+1)*PH+o1], acc1);
        acc0 = fmaf(xv.z, swp[(4*i4+2)*PH+o0], acc0);
        acc1 = fmaf(xv.z, swp[(4*i4+2)*PH+o1], acc1);
        acc0 = fmaf(xv.w, swp[(4*i4+3)*PH+o0], acc0);
        acc1 = fmaf(xv.w, swp[(4*i4+3)*PH+o1], acc1);
    }
    __half2* y2 = (__half2*)y;
    y2[((size_t)n*PH>>1) + op] = __floats2half2_rn(acc0, acc1);
}

// ---------------- shared gather-max+selu: fills o[8] for node n, chunk fg ----------------
template<int FG>
static __device__ __forceinline__ void gather_selu(const __half* __restrict__ yin,
        const int* __restrict__ row_ptr, const int* __restrict__ csr,
        int n, int fg, float o[8]){
    const uint4* yv = (const uint4*)yin;
    int beg = row_ptr[n], end = row_ptr[n+1];
    const unsigned NEG2 = 0xFC00FC00u;
    unsigned m0=NEG2, m1=NEG2, m2=NEG2, m3=NEG2;
    int j = beg;
    for(; j+4<=end; j+=4){
        int s0=csr[j], s1=csr[j+1], s2=csr[j+2], s3=csr[j+3];
        uint4 v0=yv[(size_t)s0*FG+fg], v1=yv[(size_t)s1*FG+fg];
        uint4 v2=yv[(size_t)s2*FG+fg], v3=yv[(size_t)s3*FG+fg];
        m0=pkmax(m0,v0.x); m1=pkmax(m1,v0.y); m2=pkmax(m2,v0.z); m3=pkmax(m3,v0.w);
        m0=pkmax(m0,v1.x); m1=pkmax(m1,v1.y); m2=pkmax(m2,v1.z); m3=pkmax(m3,v1.w);
        m0=pkmax(m0,v2.x); m1=pkmax(m1,v2.y); m2=pkmax(m2,v2.z); m3=pkmax(m3,v2.w);
        m0=pkmax(m0,v3.x); m1=pkmax(m1,v3.y); m2=pkmax(m2,v3.z); m3=pkmax(m3,v3.w);
    }
    for(; j<end; j++){
        uint4 v = yv[(size_t)csr[j]*FG+fg];
        m0=pkmax(m0,v.x); m1=pkmax(m1,v.y); m2=pkmax(m2,v.z); m3=pkmax(m3,v.w);
    }
    float2 f0=h2_to_f2(m0), f1=h2_to_f2(m1), f2=h2_to_f2(m2), f3=h2_to_f2(m3);
    float f[8] = {f0.x,f0.y,f1.x,f1.y,f2.x,f2.y,f3.x,f3.y};
    #pragma unroll
    for(int k=0;k<8;k++){
        float m = f[k];
        if(m < -1e30f) m = 0.0f;    // empty segment (-inf) -> 0
        o[k] = selu_f(m);
    }
}

// ---------------- fused layer: gather-max+selu -> S accum -> next transform -> fp16 yout ----------------
// 64 nodes per block, FG = PH_IN/8 threads per node.
template<int PH_IN,int D_CUR,int SOFF,int D_NEXT,int PH_NEXT>
__global__ __launch_bounds__(64*(PH_IN/8)) void k_fused(
        const __half* __restrict__ yin, const int* __restrict__ row_ptr,
        const int* __restrict__ csr, const int* __restrict__ batch,
        const float* __restrict__ W, const float* __restrict__ bias,
        float* __restrict__ S, __half* __restrict__ yout){
    const int FG = PH_IN/8;
    __shared__ float feat[64][PH_IN+1];
    __shared__ float sw[D_CUR*PH_NEXT];
    __shared__ float sb[PH_NEXT];
    __shared__ int sbatch[64];
    int t = threadIdx.x;
    int nl = t / FG, fg = t - nl*FG;
    int base = blockIdx.x*64;
    int n = base + nl;
    for(int i=t;i<D_CUR*PH_NEXT;i+=64*FG){
        int k=i/PH_NEXT, o=i-k*PH_NEXT;
        sw[i] = (o<D_NEXT) ? W[k*D_NEXT+o] : 0.f;
    }
    if(t<PH_NEXT) sb[t] = (t<D_NEXT) ? bias[t] : 0.f;
    if(t<64) sbatch[t] = (base+t<N_NODES) ? batch[base+t] : -1;
    float o[8];
    if(n < N_NODES){
        gather_selu<FG>(yin,row_ptr,csr,n,fg,o);
    } else {
        for(int k=0;k<8;k++) o[k]=0.f;
    }
    #pragma unroll
    for(int k=0;k<8;k++) feat[nl][8*fg+k] = o[k];
    __syncthreads();
    // per-graph run reduction into S (batch sorted)
    if(t < D_CUR){
        float acc=0.f; int gprev = sbatch[0];
        for(int m=0;m<64;m++){
            int g = sbatch[m];
            if(g<0) break;
            if(g!=gprev){ atomicAdd(&S[(size_t)gprev*SD+SOFF+t], acc); acc=0.f; gprev=g; }
            acc += feat[m][t];
        }
        if(gprev>=0) atomicAdd(&S[(size_t)gprev*SD+SOFF+t], acc);
    }
    // next-layer transform from LDS
    if(n < N_NODES){
        for(int o2=fg; o2<PH_NEXT/2; o2+=FG){
            int c0=2*o2, c1=c0+1;
            float a0=sb[c0], a1=sb[c1];
            #pragma unroll
            for(int k=0;k<D_CUR;k++){
                float fv = feat[nl][k];
                a0 = fmaf(fv, sw[k*PH_NEXT+c0], a0);
                a1 = fmaf(fv, sw[k*PH_NEXT+c1], a1);
            }
            ((__half2*)yout)[(size_t)n*(PH_NEXT/2)+o2] = __floats2half2_rn(a0,a1);
        }
    }
}

// ---------------- fused last layer: gather-max+selu -> S accum only ----------------
template<int PH_IN,int D_CUR,int SOFF>
__global__ __launch_bounds__(64*(PH_IN/8)) void k_fused_last(
        const __half* __restrict__ yin, const int* __restrict__ row_ptr,
        const int* __restrict__ csr, const int* __restrict__ batch,
        float* __restrict__ S){
    const int FG = PH_IN/8;
    __shared__ float feat[64][PH_IN+1];
    __shared__ int sbatch[64];
    int t = threadIdx.x;
    int nl = t / FG, fg = t - nl*FG;
    int base = blockIdx.x*64;
    int n = base + nl;
    if(t<64) sbatch[t] = (base+t<N_NODES) ? batch[base+t] : -1;
    float o[8];
    if(n < N_NODES){
        gather_selu<FG>(yin,row_ptr,csr,n,fg,o);
    } else {
        for(int k=0;k<8;k++) o[k]=0.f;
    }
    #pragma unroll
    for(int k=0;k<8;k++) feat[nl][8*fg+k] = o[k];
    __syncthreads();
    if(t < D_CUR){
        float acc=0.f; int gprev = sbatch[0];
        for(int m=0;m<64;m++){
            int g = sbatch[m];
            if(g<0) break;
            if(g!=gprev){ atomicAdd(&S[(size_t)gprev*SD+SOFF+t], acc); acc=0.f; gprev=g; }
            acc += feat[m][t];
        }
        if(gprev>=0) atomicAdd(&S[(size_t)gprev*SD+SOFF+t], acc);
    }
}

// ---------------- readout: r = S @ Wcat + sum(b) ----------------
__global__ __launch_bounds__(192) void k_readout(const float* __restrict__ S,
    const float* __restrict__ w1,const float* __restrict__ b1,
    const float* __restrict__ w2,const float* __restrict__ b2,
    const float* __restrict__ w3,const float* __restrict__ b3,
    const float* __restrict__ w4,const float* __restrict__ b4,
    float* __restrict__ r){
    __shared__ float sH[GPB][SD];
    int t = threadIdx.x;
    int g0 = blockIdx.x*GPB;
    for(int i=t;i<GPB*SD;i+=192){
        int gl=i/SD, k=i-gl*SD;
        int g=g0+gl;
        sH[gl][k] = (g<N_GRAPHS) ? S[(size_t)g*SD+k] : 0.f;
    }
    __syncthreads();
    int j = t;
    if(j < RD){
        float acc[GPB];
        float bj = b1[j]+b2[j]+b3[j]+b4[j];
        #pragma unroll
        for(int gl=0;gl<GPB;gl++) acc[gl]=bj;
        for(int k=0;k<20;k++){ float wv=w1[k*RD+j];
            #pragma unroll
            for(int gl=0;gl<GPB;gl++) acc[gl] += sH[gl][k]*wv; }
        for(int k=0;k<27;k++){ float wv=w2[k*RD+j];
            #pragma unroll
            for(int gl=0;gl<GPB;gl++) acc[gl] += sH[gl][20+k]*wv; }
        for(int k=0;k<36;k++){ float wv=w3[k*RD+j];
            #pragma unroll
            for(int gl=0;gl<GPB;gl++) acc[gl] += sH[gl][47+k]*wv; }
        for(int k=0;k<36;k++){ float wv=w4[k*RD+j];
            #pragma unroll
            for(int gl=0;gl<GPB;gl++) acc[gl] += sH[gl][83+k]*wv; }
        int ng = min(GPB, N_GRAPHS-g0);
        for(int gl=0;gl<ng;gl++) r[(size_t)(g0+gl)*RD+j] = acc[gl];
    }
}

// ---------------- fc1: z1 = [r, mol] @ w + b, + BN partial stats ----------------
__global__ __launch_bounds__(128) void k_fc1(const float* __restrict__ r, const float* __restrict__ mol,
    const float* __restrict__ w, const float* __restrict__ b,
    float* __restrict__ z1, float* __restrict__ ps, float* __restrict__ pq){
    __shared__ float sH[GPB][RD+10];
    int t = threadIdx.x;
    int g0 = blockIdx.x*GPB;
    for(int i=t;i<GPB*(RD+10);i+=128){
        int gl=i/(RD+10), k=i-gl*(RD+10);
        int g=g0+gl;
        float v=0.f;
        if(g<N_GRAPHS) v = (k<RD) ? r[(size_t)g*RD+k] : mol[(size_t)g*10 + (k-RD)];
        sH[gl][k]=v;
    }
    __syncthreads();
    int j = t;
    if(j < H1){
        float acc[GPB]; float bj=b[j];
        #pragma unroll
        for(int gl=0;gl<GPB;gl++) acc[gl]=bj;
        for(int k=0;k<RD+10;k++){
            float wv = w[k*H1+j];
            #pragma unroll
            for(int gl=0;gl<GPB;gl++) acc[gl] += sH[gl][k]*wv;
        }
        int ng = min(GPB, N_GRAPHS-g0);
        float psum=0.f, psq=0.f;
        for(int gl=0;gl<ng;gl++){
            z1[(size_t)(g0+gl)*H1+j]=acc[gl];
            psum+=acc[gl]; psq+=acc[gl]*acc[gl];
        }
        ps[blockIdx.x*H1+j]=psum;
        pq[blockIdx.x*H1+j]=psq;
    }
}

// ---------------- BN finalize: a = g/sqrt(var+eps), c = b - a*mu ----------------
__global__ __launch_bounds__(256) void k_bnfin(const float* __restrict__ ps, const float* __restrict__ pq,
    int nb, int H, const float* __restrict__ gamma, const float* __restrict__ beta,
    float* __restrict__ a, float* __restrict__ c){
    int j = blockIdx.x;
    int t = threadIdx.x;
    float s=0.f, q=0.f;
    for(int i=t;i<nb;i+=256){ s+=ps[(size_t)i*H+j]; q+=pq[(size_t)i*H+j]; }
    __shared__ float sh1[256], sh2[256];
    sh1[t]=s; sh2[t]=q; __syncthreads();
    for(int off=128;off>0;off>>=1){
        if(t<off){ sh1[t]+=sh1[t+off]; sh2[t]+=sh2[t+off]; }
        __syncthreads();
    }
    if(t==0){
        float mean = sh1[0]/(float)N_GRAPHS;
        float var  = sh2[0]/(float)N_GRAPHS - mean*mean;
        float inv  = 1.0f/sqrtf(var + 1e-5f);
        float aj = gamma[j]*inv;
        a[j]=aj; c[j]=beta[j]-aj*mean;
    }
}

// ---------------- fc2: z2 = relu(bn1(z1)) @ w + b, + BN partial stats ----------------
__global__ __launch_bounds__(64) void k_fc2(const float* __restrict__ z1, const float* __restrict__ a1,
    const float* __restrict__ c1, const float* __restrict__ w, const float* __restrict__ b,
    float* __restrict__ z2, float* __restrict__ ps, float* __restrict__ pq){
    __shared__ float sH[GPB][H1];
    int t = threadIdx.x;
    int g0 = blockIdx.x*GPB;
    for(int i=t;i<GPB*H1;i+=64){
        int gl=i/H1, k=i-gl*H1;
        int g=g0+gl;
        float v=0.f;
        if(g<N_GRAPHS){ float z=z1[(size_t)g*H1+k]; v=fmaxf(a1[k]*z+c1[k],0.f); }
        sH[gl][k]=v;
    }
    __syncthreads();
    int j = t;
    if(j < H2){
        float acc[GPB]; float bj=b[j];
        #pragma unroll
        for(int gl=0;gl<GPB;gl++) acc[gl]=bj;
        for(int k=0;k<H1;k++){
            float wv=w[k*H2+j];
            #pragma unroll
            for(int gl=0;gl<GPB;gl++) acc[gl]+=sH[gl][k]*wv;
        }
        int ng=min(GPB,N_GRAPHS-g0);
        float psum=0.f,psq=0.f;
        for(int gl=0;gl<ng;gl++){
            z2[(size_t)(g0+gl)*H2+j]=acc[gl];
            psum+=acc[gl]; psq+=acc[gl]*acc[gl];
        }
        ps[blockIdx.x*H2+j]=psum; pq[blockIdx.x*H2+j]=psq;
    }
}

// ---------------- out: sigmoid(relu(bn2(z2)) @ w + b) ----------------
__global__ __launch_bounds__(192) void k_out(const float* __restrict__ z2, const float* __restrict__ a2,
    const float* __restrict__ c2, const float* __restrict__ w, const float* __restrict__ b,
    float* __restrict__ out){
    __shared__ float sH[GPB][H2];
    int t = threadIdx.x;
    int g0 = blockIdx.x*GPB;
    for(int i=t;i<GPB*H2;i+=192){
        int gl=i/H2, k=i-gl*H2;
        int g=g0+gl;
        float v=0.f;
        if(g<N_GRAPHS){ float z=z2[(size_t)g*H2+k]; v=fmaxf(a2[k]*z+c2[k],0.f); }
        sH[gl][k]=v;
    }
    __syncthreads();
    int j = t;
    if(j < NT){
        float acc[GPB]; float bj=b[j];
        #pragma unroll
        for(int gl=0;gl<GPB;gl++) acc[gl]=bj;
        for(int k=0;k<H2;k++){
            float wv=w[k*NT+j];
            #pragma unroll
            for(int gl=0;gl<GPB;gl++) acc[gl]+=sH[gl][k]*wv;
        }
        int ng=min(GPB,N_GRAPHS-g0);
        for(int gl=0;gl<ng;gl++)
            out[(size_t)(g0+gl)*NT+j] = 1.0f/(1.0f+__expf(-acc[gl]));
    }
}

// ---------------- launcher ----------------
static inline int ceil_div(int a,int b){ return (a+b-1)/b; }

extern "C" void kernel_launch(void* const* d_in, const int* in_sizes, int n_in,
                              void* d_out, int out_size, void* d_ws, size_t ws_size,
                              hipStream_t stream) {
    const float* x     = (const float*)d_in[0];
    const float* mol   = (const float*)d_in[1];
    const int*   ei    = (const int*)  d_in[2];   // [0:E]=src, [E:2E]=dst
    const int*   batch = (const int*)  d_in[3];
    const float* w_g1=(const float*)d_in[4];  const float* b_g1=(const float*)d_in[5];
    const float* w_g2=(const float*)d_in[6];  const float* b_g2=(const float*)d_in[7];
    const float* w_g3=(const float*)d_in[8];  const float* b_g3=(const float*)d_in[9];
    const float* w_g4=(const float*)d_in[10]; const float* b_g4=(const float*)d_in[11];
    const float* w_r1=(const float*)d_in[12]; const float* b_r1=(const float*)d_in[13];
    const float* w_r2=(const float*)d_in[14]; const float* b_r2=(const float*)d_in[15];
    const float* w_r3=(const float*)d_in[16]; const float* b_r3=(const float*)d_in[17];
    const float* w_r4=(const float*)d_in[18]; const float* b_r4=(const float*)d_in[19];
    const float* w_fc1=(const float*)d_in[20]; const float* b_fc1=(const float*)d_in[21];
    const float* bn1_g=(const float*)d_in[22]; const float* bn1_b=(const float*)d_in[23];
    const float* w_fc2=(const float*)d_in[24]; const float* b_fc2=(const float*)d_in[25];
    const float* bn2_g=(const float*)d_in[26]; const float* bn2_b=(const float*)d_in[27];
    const float* w_out=(const float*)d_in[28]; const float* b_out=(const float*)d_in[29];
    float* out = (float*)d_out;

    // workspace carve-up (256B aligned regions)
    char* p = (char*)d_ws;
    auto take=[&](size_t bytes)->char*{ char* q=p; p += (bytes+255)&~(size_t)255; return q; };
    __half* yA = (__half*)take((size_t)N_NODES*40*2);
    __half* yB = (__half*)take((size_t)N_NODES*40*2);
    int* chist   = (int*)take((size_t)NBUCK2*4);
    int* cptr    = (int*)take((size_t)(NBUCK2+1)*4);
    int* bcur    = (int*)take((size_t)NBUCK2*4);
    int* row_ptr = (int*)take((size_t)(N_NODES+1)*4);
    int* packed  = (int*)take((size_t)N_EDGES*4);
    int* csr     = (int*)take((size_t)N_EDGES*4);
    float* S  = (float*)take((size_t)N_GRAPHS*SD*4);
    float* r  = (float*)take((size_t)N_GRAPHS*RD*4);
    float* z1 = (float*)take((size_t)N_GRAPHS*H1*4);
    float* z2 = (float*)take((size_t)N_GRAPHS*H2*4);
    const int NB_G = ceil_div(N_GRAPHS, GPB);   // 1563
    float* p1s=(float*)take((size_t)NB_G*H1*4);
    float* p1q=(float*)take((size_t)NB_G*H1*4);
    float* p2s=(float*)take((size_t)NB_G*H2*4);
    float* p2q=(float*)take((size_t)NB_G*H2*4);
    float* a1=(float*)take(H1*4); float* c1=(float*)take(H1*4);
    float* a2=(float*)take(H2*4); float* c2=(float*)take(H2*4);

    const int* src = ei;
    const int* dst = ei + N_EDGES;

    // ---- CSR build + S zero ----
    k_init<<<ceil_div(N_GRAPHS*SD,256),256,0,stream>>>(chist,S);
    k_chist<<<NB_BIN,256,0,stream>>>(dst,chist);
    k_cscan<<<1,256,0,stream>>>(chist,cptr,bcur);
    k_bin<<<NB_BIN,256,0,stream>>>(src,dst,bcur,packed);
    k_scatfine<<<NBUCK2,1024,0,stream>>>(cptr,packed,row_ptr,csr);

    // layer 1 transform: x(48 fp32) -> yA(fp16 PH=24, D=20)
    k_transform_h<48,20,48,24><<<ceil_div(N_NODES*12,256),256,0,stream>>>(x,w_g1,b_g1,yA);
    // fused layers: gather + selu + S accum + next transform
    k_fused<24,20,0, 27,32><<<NBF,192,0,stream>>>(yA,row_ptr,csr,batch,w_g2,b_g2,S,yB);
    k_fused<32,27,20,36,40><<<NBF,256,0,stream>>>(yB,row_ptr,csr,batch,w_g3,b_g3,S,yA);
    k_fused<40,36,47,36,40><<<NBF,320,0,stream>>>(yA,row_ptr,csr,batch,w_g4,b_g4,S,yB);
    k_fused_last<40,36,83><<<NBF,320,0,stream>>>(yB,row_ptr,csr,batch,S);

    k_readout<<<NB_G,192,0,stream>>>(S,w_r1,b_r1,w_r2,b_r2,w_r3,b_r3,w_r4,b_r4,r);
    k_fc1<<<NB_G,128,0,stream>>>(r,mol,w_fc1,b_fc1,z1,p1s,p1q);
    k_bnfin<<<H1,256,0,stream>>>(p1s,p1q,NB_G,H1,bn1_g,bn1_b,a1,c1);
    k_fc2<<<NB_G,64,0,stream>>>(z1,a1,c1,w_fc2,b_fc2,z2,p2s,p2q);
    k_bnfin<<<H2,256,0,stream>>>(p2s,p2q,NB_G,H2,bn2_g,bn2_b,a2,c2);
    k_out<<<NB_G,192,0,stream>>>(z2,a2,c2,w_out,b_out,out);
}